// Round 4
// baseline (234.329 us; speedup 1.0000x reference)
//
#include <hip/hip_runtime.h>

#define BATCH 32
#define CH 3
#define HH 256
#define WW 256
#define KS 29
#define PAD 14
#define NT_F 1000.0f

typedef __attribute__((ext_vector_type(8))) short short8;
typedef __attribute__((ext_vector_type(4))) float f32x4;

union U4 { short8 s8; uint4 u4; };

__device__ inline unsigned short bf16rne(float f) {
  unsigned u = __float_as_uint(f);
  unsigned r = (u + 0x7FFFu + ((u >> 16) & 1u)) >> 16;
  return (unsigned short)r;
}
__device__ inline float bf16tof(unsigned s) {
  return __uint_as_float(s << 16);
}

// ws float layout:
//   gk    [32][32]            @ 0
//   tcond [32][32]            @ 1024
//   w1k   ushort[32][32]      @ 2048  (B-frag-ready conv1 weights, custom k-order)
//   w1g   ushort[32][4]       @ 2560  (conv1 leftover tap (dy2,dx2), ci padded 4)
//   w2b   ushort[3][16][32]   @ 2624  ([dy][n=dx*4+oc][och])
//   z     ushort[32][3][256][256] @ 3392  (bf16 blurred)
//
// conv1 k-order (k = q*8+j, q=k>>3, j=k&7, ci=j&3):
//   q<3 : tap (dy=q,  dx=j>>2, ci)   [ci==3 -> pad 0]
//   q==3: tap (dy=j>>2, dx=2,  ci)
//   second MFMA (K=4 used): k j0..3 = (dy=2, dx=2, ci)

// ---------------- prep ----------------
__global__ void prep_kernel(const float* __restrict__ sched,
                            const int* __restrict__ t,
                            const float* __restrict__ W1,
                            const float* __restrict__ b1,
                            const float* __restrict__ tw,
                            const float* __restrict__ W2,
                            float* __restrict__ ws, float* __restrict__ out) {
  int tid = threadIdx.x;
  if (tid == 0) out[0] = 0.0f;
  float* gk = ws;
  float* tcond = ws + 1024;
  unsigned short* w1k = (unsigned short*)(ws + 2048);
  unsigned short* w1g = (unsigned short*)(ws + 2560);
  unsigned short* w2b = (unsigned short*)(ws + 2624);
  if (tid < BATCH) {
    float sigma = sched[t[tid]];
    float inv = 1.0f / sigma;
    float wv[KS];
    float s = 0.0f;
#pragma unroll
    for (int i = 0; i < KS; i++) {
      float xg = (float)(i - PAD) * inv;
      wv[i] = expf(-0.5f * xg * xg);
      s += wv[i];
    }
    float rs = 1.0f / s;
#pragma unroll
    for (int i = 0; i < KS; i++) gk[tid * 32 + i] = wv[i] * rs;
  }
  for (int i = tid; i < 1024; i += 256) {          // w1k
    int o = i >> 5, k = i & 31;
    int q = k >> 3, j = k & 7, ci = j & 3;
    int dy, dx;
    if (q < 3) { dy = q; dx = j >> 2; } else { dy = j >> 2; dx = 2; }
    w1k[i] = (ci < 3) ? bf16rne(W1[o * 27 + ci * 9 + dy * 3 + dx]) : (unsigned short)0;
  }
  for (int i = tid; i < 128; i += 256) {           // w1g
    int o = i >> 2, j = i & 3;
    w1g[i] = (j < 3) ? bf16rne(W1[o * 27 + j * 9 + 8]) : (unsigned short)0;
  }
  for (int i = tid; i < 1536; i += 256) {          // w2b
    int dy = i / 512, r = i & 511;
    int n = r >> 5, och = r & 31;
    int dx = n >> 2, oc = n & 3;
    w2b[i] = (dx < 3 && oc < 3)
                 ? bf16rne(W2[((oc * 32 + och) * 3 + dy) * 3 + dx])
                 : (unsigned short)0;
  }
  for (int i = tid; i < 1024; i += 256) {          // tcond
    int b = i >> 5, o = i & 31;
    tcond[i] = b1[o] + ((float)t[b] * (1.0f / NT_F)) * tw[o];
  }
}

// ---------------- blur: register vertical + b128 horizontal, bf16 out -------
__global__ __launch_bounds__(256) void blur_kernel(const float* __restrict__ x,
                                                   const float* __restrict__ ws,
                                                   unsigned short* __restrict__ z) {
  __shared__ float vsp[16][288];   // padded cols: idx = col + 16
  int blk = blockIdx.x;
  int rg = blk & 15;
  int bc = blk >> 4;
  int b = bc / CH;
  int y0 = rg * 16;
  int tid = threadIdx.x;
  const float* xp = x + (size_t)bc * (HH * WW);
  const float* kb = ws + b * 32;   // uniform -> s_load

  float xv[44];
#pragma unroll
  for (int i = 0; i < 44; i++) {
    int gy = y0 - PAD + i;
    gy = (gy < 0) ? -gy : gy;
    gy = (gy >= HH) ? (2 * HH - 2 - gy) : gy;
    xv[i] = xp[gy * WW + tid];
  }
  float acc[16];
#pragma unroll
  for (int yy = 0; yy < 16; yy++) acc[yy] = 0.0f;
#pragma unroll
  for (int kk = 0; kk < KS; kk++) {
    float kv = kb[kk];
#pragma unroll
    for (int yy = 0; yy < 16; yy++) acc[yy] += kv * xv[yy + kk];
  }
#pragma unroll
  for (int yy = 0; yy < 16; yy++) vsp[yy][tid + 16] = acc[yy];
  __syncthreads();
  {
    int row = tid >> 4, i2 = tid & 15;
    vsp[row][i2] = vsp[row][32 - i2];
    vsp[row][272 + i2] = vsp[row][270 - i2];
  }
  __syncthreads();

  size_t zb = (size_t)bc * (HH * WW);
#pragma unroll
  for (int it = 0; it < 4; ++it) {
    int unit = tid + 256 * it;
    int row = unit >> 6, cg = unit & 63;
    float w[36];
#pragma unroll
    for (int i = 0; i < 9; i++)
      *(float4*)&w[4 * i] = *(const float4*)&vsp[row][4 * (cg + i)];
    float o0 = 0, o1 = 0, o2 = 0, o3 = 0;
#pragma unroll
    for (int kk = 0; kk < KS; kk++) {
      float kv = kb[kk];
      o0 += kv * w[2 + kk];
      o1 += kv * w[3 + kk];
      o2 += kv * w[4 + kk];
      o3 += kv * w[5 + kk];
    }
    unsigned u0 = (unsigned)bf16rne(o0) | ((unsigned)bf16rne(o1) << 16);
    unsigned u1 = (unsigned)bf16rne(o2) | ((unsigned)bf16rne(o3) << 16);
    *(uint2*)&z[zb + (size_t)(y0 + row) * WW + 4 * cg] = make_uint2(u0, u1);
  }
}

// ---------------- fused conv1+ReLU+conv2+MSE via bf16 MFMA ----------------
// grid (16,16,B); block 256 = 4 waves; 16x16 output tile
__global__ __launch_bounds__(256, 4) void convloss_kernel(
    const float* __restrict__ x, const float* __restrict__ ws,
    const float* __restrict__ b2g, float* __restrict__ out) {
  __shared__ unsigned short zs4[400 * 4];   // [y*20+x][ci0..2,pad] bf16, 3200B
  __shared__ unsigned short hs[324 * 36];   // [p][och], 23328B
  __shared__ unsigned short EsT[12 * 324];  // [n][p] one dy at a time, 7776B
  __shared__ float wsum[4];

  const float* tcond = ws + 1024;
  const unsigned short* w1k = (const unsigned short*)(ws + 2048);
  const unsigned short* w1g = (const unsigned short*)(ws + 2560);
  const unsigned short* w2b = (const unsigned short*)(ws + 2624);
  const unsigned short* zg = (const unsigned short*)(ws + 3392);

  int bx = blockIdx.x, by = blockIdx.y, b = blockIdx.z;
  int tid = threadIdx.x;
  int x0 = bx * 16, y0 = by * 16;
  const unsigned short* zbp = zg + (size_t)b * 3 * HH * WW;

  // stage z tile, channel-interleaved, zero pad slot + zero outside image
#pragma unroll
  for (int r = 0; r < 2; r++) {
    int unit = tid + 256 * r;
    if (unit < 400) {
      int zy = unit / 20, zx = unit - zy * 20;
      int gy = y0 - 2 + zy, gx = x0 - 2 + zx;
      unsigned c0 = 0, c1 = 0, c2 = 0;
      if ((unsigned)gy < (unsigned)HH && (unsigned)gx < (unsigned)WW) {
        int gi = gy * WW + gx;
        c0 = zbp[gi];
        c1 = zbp[HH * WW + gi];
        c2 = zbp[2 * HH * WW + gi];
      }
      *(uint2*)&zs4[unit * 4] = make_uint2(c0 | (c1 << 16), c2);
    }
  }

  int lane = tid & 63;
  int q = lane >> 4;        // quad 0..3
  int col = lane & 15;      // MFMA m/n index
  int wv = tid >> 6;        // wave id

  // B fragments (uniform-stride vector loads from global ws)
  U4 B1a, B1b, B2a, B2b, B2c[3];
  B1a.u4 = *(const uint4*)(w1k + col * 32 + q * 8);
  B1b.u4 = *(const uint4*)(w1k + (col + 16) * 32 + q * 8);
  {
    uint2 ta = *(const uint2*)(w1g + col * 4);
    uint2 tb = *(const uint2*)(w1g + (col + 16) * 4);
    bool q0 = (q == 0);
    B2a.u4 = make_uint4(q0 ? ta.x : 0u, q0 ? ta.y : 0u, 0u, 0u);
    B2b.u4 = make_uint4(q0 ? tb.x : 0u, q0 ? tb.y : 0u, 0u, 0u);
  }
#pragma unroll
  for (int dy = 0; dy < 3; dy++)
    B2c[dy].u4 = *(const uint4*)(w2b + dy * 512 + col * 32 + q * 8);
  float tc0 = tcond[b * 32 + col];
  float tc1 = tcond[b * 32 + 16 + col];

  __syncthreads();

  const f32x4 zero4 = {0.0f, 0.0f, 0.0f, 0.0f};
  int dyq = (q < 3) ? q : 0;
  int dxq = (q < 3) ? 0 : 2;
  int strB = (q < 3) ? 4 : 80;   // ushort delta: dx+1 or next row (q3)

  // ---- P1: conv1 -> h (18x18, 32 och) ----
  for (int g = wv; g < 21; g += 4) {
    int p = g * 16 + col;
    if (p > 323) p = 323;
    int py = p / 18, px = p - py * 18;
    int a0 = ((py + dyq) * 20 + px + dxq) * 4;
    uint2 lo = *(const uint2*)&zs4[a0];
    uint2 hi = *(const uint2*)&zs4[a0 + strB];
    U4 A1;
    A1.u4 = make_uint4(lo.x, lo.y, hi.x, hi.y);
    uint2 t2 = *(const uint2*)&zs4[((py + 2) * 20 + px + 2) * 4];
    U4 A2;
    bool q0 = (q == 0);
    A2.u4 = make_uint4(q0 ? t2.x : 0u, q0 ? t2.y : 0u, 0u, 0u);
    f32x4 acc0 = __builtin_amdgcn_mfma_f32_16x16x32_bf16(A1.s8, B1a.s8, zero4, 0, 0, 0);
    acc0 = __builtin_amdgcn_mfma_f32_16x16x32_bf16(A2.s8, B2a.s8, acc0, 0, 0, 0);
    f32x4 acc1 = __builtin_amdgcn_mfma_f32_16x16x32_bf16(A1.s8, B1b.s8, zero4, 0, 0, 0);
    acc1 = __builtin_amdgcn_mfma_f32_16x16x32_bf16(A2.s8, B2b.s8, acc1, 0, 0, 0);
    int prow = g * 16 + q * 4;
#pragma unroll
    for (int r = 0; r < 4; r++) {
      int pw = prow + r;
      if (pw < 324) {
        hs[pw * 36 + col] = bf16rne(fmaxf(acc0[r] + tc0, 0.0f));
        hs[pw * 36 + col + 16] = bf16rne(fmaxf(acc1[r] + tc1, 0.0f));
      }
    }
  }
  __syncthreads();

  // ---- preload conv2 A-fragments ----
  U4 A2h[6];
  int ng = 0;
  for (int g = wv; g < 21; g += 4, ng++) {
    int p = g * 16 + col;
    if (p > 323) p = 323;
    uint2 u0 = *(const uint2*)&hs[p * 36 + q * 8];
    uint2 u1 = *(const uint2*)&hs[p * 36 + q * 8 + 4];
    A2h[ng].u4 = make_uint4(u0.x, u0.y, u1.x, u1.y);
  }

  // ---- conv2 + gather, one dy plane at a time ----
  int ty = tid >> 4, tx = tid & 15;
  float c0 = b2g[0], c1 = b2g[1], c2 = b2g[2];
#pragma unroll
  for (int dy = 0; dy < 3; dy++) {
    int i = 0;
    for (int g = wv; g < 21; g += 4, i++) {
      f32x4 e = __builtin_amdgcn_mfma_f32_16x16x32_bf16(A2h[i].s8, B2c[dy].s8, zero4, 0, 0, 0);
      int prow = g * 16 + q * 4;
      if (col < 12 && prow < 324) {
        unsigned v0 = (unsigned)bf16rne(e[0]) | ((unsigned)bf16rne(e[1]) << 16);
        unsigned v1 = (unsigned)bf16rne(e[2]) | ((unsigned)bf16rne(e[3]) << 16);
        *(uint2*)&EsT[col * 324 + prow] = make_uint2(v0, v1);
      }
    }
    __syncthreads();
    int pr = (ty + dy) * 18 + tx;
#pragma unroll
    for (int dx = 0; dx < 3; dx++) {
      int pp = pr + dx;
      c0 += bf16tof(EsT[(dx * 4 + 0) * 324 + pp]);
      c1 += bf16tof(EsT[(dx * 4 + 1) * 324 + pp]);
      c2 += bf16tof(EsT[(dx * 4 + 2) * 324 + pp]);
    }
    __syncthreads();
  }

  // ---- MSE ----
  int gy = y0 + ty, gx = x0 + tx;
  const float* xb = x + (size_t)b * 3 * HH * WW;
  float d0 = xb[gy * WW + gx] - c0;
  float d1 = xb[HH * WW + gy * WW + gx] - c1;
  float d2 = xb[2 * HH * WW + gy * WW + gx] - c2;
  float s = d0 * d0 + d1 * d1 + d2 * d2;
#pragma unroll
  for (int off = 32; off > 0; off >>= 1) s += __shfl_down(s, off);
  if (lane == 0) wsum[wv] = s;
  __syncthreads();
  if (tid == 0) {
    float tot = wsum[0] + wsum[1] + wsum[2] + wsum[3];
    atomicAdd(out, tot * (1.0f / 6291456.0f));
  }
}

extern "C" void kernel_launch(void* const* d_in, const int* in_sizes, int n_in,
                              void* d_out, int out_size, void* d_ws, size_t ws_size,
                              hipStream_t stream) {
  const float* x = (const float*)d_in[0];
  const int* t = (const int*)d_in[1];
  const float* W1 = (const float*)d_in[2];
  const float* b1 = (const float*)d_in[3];
  const float* tw = (const float*)d_in[4];
  const float* W2 = (const float*)d_in[5];
  const float* b2 = (const float*)d_in[6];
  const float* sched = (const float*)d_in[7];
  float* out = (float*)d_out;
  float* ws = (float*)d_ws;
  unsigned short* z = (unsigned short*)(ws + 3392);

  prep_kernel<<<1, 256, 0, stream>>>(sched, t, W1, b1, tw, W2, ws, out);
  blur_kernel<<<BATCH * CH * 16, 256, 0, stream>>>(x, ws, z);
  dim3 grid(16, 16, BATCH);
  convloss_kernel<<<grid, 256, 0, stream>>>(x, ws, b2, out);
}

// Round 5
// 218.065 us; speedup vs baseline: 1.0746x; 1.0746x over previous
//
#include <hip/hip_runtime.h>

#define BATCH 32
#define CH 3
#define HH 256
#define WW 256
#define KS 29
#define PAD 14
#define NT_F 1000.0f

typedef __attribute__((ext_vector_type(8))) short short8;
typedef __attribute__((ext_vector_type(4))) float f32x4;

union U4 { short8 s8; uint4 u4; };

__device__ inline unsigned short bf16rne(float f) {
  unsigned u = __float_as_uint(f);
  unsigned r = (u + 0x7FFFu + ((u >> 16) & 1u)) >> 16;
  return (unsigned short)r;
}
__device__ inline float bf16tof(unsigned s) {
  return __uint_as_float(s << 16);
}

// ws float layout:
//   gk    [32][32]            @ 0
//   tcond [32][32]            @ 1024
//   w1k   ushort[32][32]      @ 2048  (B-frag-ready conv1 weights, custom k-order)
//   w1g   ushort[32][4]       @ 2560  (conv1 leftover tap (dy2,dx2), ci padded 4)
//   w2b   ushort[3][16][32]   @ 2624  ([dy][n=dx*4+oc][och])
//   z     ushort[32][3][256][256] @ 3392  (bf16 blurred)
//
// conv1 k-order (k = q*8+j, q=k>>3, j=k&7, ci=j&3):
//   q<3 : tap (dy=q,  dx=j>>2, ci)   [ci==3 -> pad 0]
//   q==3: tap (dy=j>>2, dx=2,  ci)
//   second MFMA (K=4 used): j0..3 = (dy=2, dx=2, ci)

// ---------------- prep ----------------
__global__ void prep_kernel(const float* __restrict__ sched,
                            const int* __restrict__ t,
                            const float* __restrict__ W1,
                            const float* __restrict__ b1,
                            const float* __restrict__ tw,
                            const float* __restrict__ W2,
                            float* __restrict__ ws, float* __restrict__ out) {
  int tid = threadIdx.x;
  if (tid == 0) out[0] = 0.0f;
  float* gk = ws;
  float* tcond = ws + 1024;
  unsigned short* w1k = (unsigned short*)(ws + 2048);
  unsigned short* w1g = (unsigned short*)(ws + 2560);
  unsigned short* w2b = (unsigned short*)(ws + 2624);
  if (tid < BATCH) {
    float sigma = sched[t[tid]];
    float inv = 1.0f / sigma;
    float wv[KS];
    float s = 0.0f;
#pragma unroll
    for (int i = 0; i < KS; i++) {
      float xg = (float)(i - PAD) * inv;
      wv[i] = expf(-0.5f * xg * xg);
      s += wv[i];
    }
    float rs = 1.0f / s;
#pragma unroll
    for (int i = 0; i < KS; i++) gk[tid * 32 + i] = wv[i] * rs;
  }
  for (int i = tid; i < 1024; i += 256) {          // w1k
    int o = i >> 5, k = i & 31;
    int q = k >> 3, j = k & 7, ci = j & 3;
    int dy, dx;
    if (q < 3) { dy = q; dx = j >> 2; } else { dy = j >> 2; dx = 2; }
    w1k[i] = (ci < 3) ? bf16rne(W1[o * 27 + ci * 9 + dy * 3 + dx]) : (unsigned short)0;
  }
  for (int i = tid; i < 128; i += 256) {           // w1g
    int o = i >> 2, j = i & 3;
    w1g[i] = (j < 3) ? bf16rne(W1[o * 27 + j * 9 + 8]) : (unsigned short)0;
  }
  for (int i = tid; i < 1536; i += 256) {          // w2b
    int dy = i / 512, r = i & 511;
    int n = r >> 5, och = r & 31;
    int dx = n >> 2, oc = n & 3;
    w2b[i] = (dx < 3 && oc < 3)
                 ? bf16rne(W2[((oc * 32 + och) * 3 + dy) * 3 + dx])
                 : (unsigned short)0;
  }
  for (int i = tid; i < 1024; i += 256) {          // tcond
    int b = i >> 5, o = i & 31;
    tcond[i] = b1[o] + ((float)t[b] * (1.0f / NT_F)) * tw[o];
  }
}

// ---------------- blur: 32-row groups, register vertical, bf16 out ----------
__global__ __launch_bounds__(256, 3) void blur_kernel(const float* __restrict__ x,
                                                      const float* __restrict__ ws,
                                                      unsigned short* __restrict__ z) {
  __shared__ float vsp[32][288];   // padded cols: idx = col + 16
  int blk = blockIdx.x;            // bc*8 + rg
  int rg = blk & 7;
  int bc = blk >> 3;
  int b = bc / CH;
  int y0 = rg * 32;
  int tid = threadIdx.x;
  const float* xp = x + (size_t)bc * (HH * WW);
  const float* kb = ws + b * 32;   // uniform -> s_load

  float xv[60];
#pragma unroll
  for (int i = 0; i < 60; i++) {
    int gy = y0 - PAD + i;
    gy = (gy < 0) ? -gy : gy;
    gy = (gy >= HH) ? (2 * HH - 2 - gy) : gy;
    xv[i] = xp[gy * WW + tid];
  }
  float acc[32];
#pragma unroll
  for (int yy = 0; yy < 32; yy++) acc[yy] = 0.0f;
#pragma unroll
  for (int kk = 0; kk < KS; kk++) {
    float kv = kb[kk];
#pragma unroll
    for (int yy = 0; yy < 32; yy++) acc[yy] += kv * xv[yy + kk];
  }
#pragma unroll
  for (int yy = 0; yy < 32; yy++) vsp[yy][tid + 16] = acc[yy];
  __syncthreads();
  {
    int row = tid >> 4, i2 = tid & 15;
#pragma unroll
    for (int r2 = 0; r2 < 2; r2++) {
      int rr = row + 16 * r2;
      vsp[rr][i2] = vsp[rr][32 - i2];
      vsp[rr][272 + i2] = vsp[rr][270 - i2];
    }
  }
  __syncthreads();

  size_t zb = (size_t)bc * (HH * WW);
#pragma unroll
  for (int it = 0; it < 8; ++it) {
    int unit = tid + 256 * it;
    int row = unit >> 6, cg = unit & 63;
    float w[36];
#pragma unroll
    for (int i = 0; i < 9; i++)
      *(float4*)&w[4 * i] = *(const float4*)&vsp[row][4 * (cg + i)];
    float o0 = 0, o1 = 0, o2 = 0, o3 = 0;
#pragma unroll
    for (int kk = 0; kk < KS; kk++) {
      float kv = kb[kk];
      o0 += kv * w[2 + kk];
      o1 += kv * w[3 + kk];
      o2 += kv * w[4 + kk];
      o3 += kv * w[5 + kk];
    }
    unsigned u0 = (unsigned)bf16rne(o0) | ((unsigned)bf16rne(o1) << 16);
    unsigned u1 = (unsigned)bf16rne(o2) | ((unsigned)bf16rne(o3) << 16);
    *(uint2*)&z[zb + (size_t)(y0 + row) * WW + 4 * cg] = make_uint2(u0, u1);
  }
}

// ---------------- fused conv1+ReLU+conv2+MSE via bf16 MFMA ----------------
// grid (16,16,B); block 256 = 4 waves; 16x16 output tile
__global__ __launch_bounds__(256, 4) void convloss_kernel(
    const float* __restrict__ x, const float* __restrict__ ws,
    const float* __restrict__ b2g, float* __restrict__ out) {
  __shared__ unsigned short zs4[400 * 4];   // [y*20+x][ci0..2,pad] bf16
  __shared__ unsigned short hs[324 * 36];   // [p][och]
  __shared__ unsigned short EsT[12 * 324];  // [n][p], one dy at a time
  __shared__ float wsum[4];

  const float* tcond = ws + 1024;
  const unsigned short* w1k = (const unsigned short*)(ws + 2048);
  const unsigned short* w1g = (const unsigned short*)(ws + 2560);
  const unsigned short* w2b = (const unsigned short*)(ws + 2624);
  const unsigned short* zg = (const unsigned short*)(ws + 3392);

  int bx = blockIdx.x, by = blockIdx.y, b = blockIdx.z;
  int tid = threadIdx.x;
  int x0 = bx * 16, y0 = by * 16;
  const unsigned short* zbp = zg + (size_t)b * 3 * HH * WW;

  // stage z tile, channel-interleaved, zero pad slot + zero outside image
#pragma unroll
  for (int r = 0; r < 2; r++) {
    int unit = tid + 256 * r;
    if (unit < 400) {
      int zy = unit / 20, zx = unit - zy * 20;
      int gy = y0 - 2 + zy, gx = x0 - 2 + zx;
      unsigned c0 = 0, c1 = 0, c2 = 0;
      if ((unsigned)gy < (unsigned)HH && (unsigned)gx < (unsigned)WW) {
        int gi = gy * WW + gx;
        c0 = zbp[gi];
        c1 = zbp[HH * WW + gi];
        c2 = zbp[2 * HH * WW + gi];
      }
      *(uint2*)&zs4[unit * 4] = make_uint2(c0 | (c1 << 16), c2);
    }
  }

  int lane = tid & 63;
  int q = lane >> 4;        // quad 0..3
  int col = lane & 15;      // MFMA m/n index
  int wv = tid >> 6;        // wave id

  // B fragments (uniform-stride vector loads from global ws)
  U4 B1a, B1b, B2a, B2b, B2c[3];
  B1a.u4 = *(const uint4*)(w1k + col * 32 + q * 8);
  B1b.u4 = *(const uint4*)(w1k + (col + 16) * 32 + q * 8);
  {
    uint2 ta = *(const uint2*)(w1g + col * 4);
    uint2 tb = *(const uint2*)(w1g + (col + 16) * 4);
    bool q0 = (q == 0);
    B2a.u4 = make_uint4(q0 ? ta.x : 0u, q0 ? ta.y : 0u, 0u, 0u);
    B2b.u4 = make_uint4(q0 ? tb.x : 0u, q0 ? tb.y : 0u, 0u, 0u);
  }
#pragma unroll
  for (int dy = 0; dy < 3; dy++)
    B2c[dy].u4 = *(const uint4*)(w2b + dy * 512 + col * 32 + q * 8);
  float tc0 = tcond[b * 32 + col];
  float tc1 = tcond[b * 32 + 16 + col];

  __syncthreads();

  const f32x4 zero4 = {0.0f, 0.0f, 0.0f, 0.0f};
  int dyq = (q < 3) ? q : 0;
  int dxq = (q < 3) ? 0 : 2;
  int strB = (q < 3) ? 4 : 80;   // ushort delta: dx+1 or next row (q3)

  // ---- P1: conv1 -> h (18x18, 32 och); fully unrolled, compile-time i ----
#pragma unroll
  for (int i = 0; i < 6; i++) {
    int g = wv + 4 * i;
    if (g < 21) {                 // wave-uniform guard
      int p = g * 16 + col;
      if (p > 323) p = 323;
      int py = p / 18, px = p - py * 18;
      int a0 = ((py + dyq) * 20 + px + dxq) * 4;
      uint2 lo = *(const uint2*)&zs4[a0];
      uint2 hi = *(const uint2*)&zs4[a0 + strB];
      U4 A1;
      A1.u4 = make_uint4(lo.x, lo.y, hi.x, hi.y);
      uint2 t2 = *(const uint2*)&zs4[((py + 2) * 20 + px + 2) * 4];
      U4 A2;
      bool q0 = (q == 0);
      A2.u4 = make_uint4(q0 ? t2.x : 0u, q0 ? t2.y : 0u, 0u, 0u);
      f32x4 acc0 = __builtin_amdgcn_mfma_f32_16x16x32_bf16(A1.s8, B1a.s8, zero4, 0, 0, 0);
      acc0 = __builtin_amdgcn_mfma_f32_16x16x32_bf16(A2.s8, B2a.s8, acc0, 0, 0, 0);
      f32x4 acc1 = __builtin_amdgcn_mfma_f32_16x16x32_bf16(A1.s8, B1b.s8, zero4, 0, 0, 0);
      acc1 = __builtin_amdgcn_mfma_f32_16x16x32_bf16(A2.s8, B2b.s8, acc1, 0, 0, 0);
      int prow = g * 16 + q * 4;
#pragma unroll
      for (int r = 0; r < 4; r++) {
        int pw = prow + r;
        if (pw < 324) {
          hs[pw * 36 + col] = bf16rne(fmaxf(acc0[r] + tc0, 0.0f));
          hs[pw * 36 + col + 16] = bf16rne(fmaxf(acc1[r] + tc1, 0.0f));
        }
      }
    }
  }
  __syncthreads();

  // ---- preload conv2 A-fragments (compile-time indices -> registers) ----
  U4 A2h[6];
#pragma unroll
  for (int i = 0; i < 6; i++) {
    int g = wv + 4 * i;
    int p = g * 16 + col;
    if (p > 323) p = 323;
    uint2 u0 = *(const uint2*)&hs[p * 36 + q * 8];
    uint2 u1 = *(const uint2*)&hs[p * 36 + q * 8 + 4];
    A2h[i].u4 = make_uint4(u0.x, u0.y, u1.x, u1.y);
  }

  // ---- conv2 + gather, one dy plane at a time ----
  int ty = tid >> 4, tx = tid & 15;
  float c0 = b2g[0], c1 = b2g[1], c2 = b2g[2];
#pragma unroll
  for (int dy = 0; dy < 3; dy++) {
#pragma unroll
    for (int i = 0; i < 6; i++) {
      int g = wv + 4 * i;
      if (g < 21) {               // wave-uniform guard
        f32x4 e = __builtin_amdgcn_mfma_f32_16x16x32_bf16(A2h[i].s8, B2c[dy].s8, zero4, 0, 0, 0);
        int prow = g * 16 + q * 4;
        if (col < 12 && prow < 324) {
          unsigned v0 = (unsigned)bf16rne(e[0]) | ((unsigned)bf16rne(e[1]) << 16);
          unsigned v1 = (unsigned)bf16rne(e[2]) | ((unsigned)bf16rne(e[3]) << 16);
          *(uint2*)&EsT[col * 324 + prow] = make_uint2(v0, v1);
        }
      }
    }
    __syncthreads();
    int pr = (ty + dy) * 18 + tx;
#pragma unroll
    for (int dx = 0; dx < 3; dx++) {
      int pp = pr + dx;
      c0 += bf16tof(EsT[(dx * 4 + 0) * 324 + pp]);
      c1 += bf16tof(EsT[(dx * 4 + 1) * 324 + pp]);
      c2 += bf16tof(EsT[(dx * 4 + 2) * 324 + pp]);
    }
    __syncthreads();
  }

  // ---- MSE ----
  int gy = y0 + ty, gx = x0 + tx;
  const float* xb = x + (size_t)b * 3 * HH * WW;
  float d0 = xb[gy * WW + gx] - c0;
  float d1 = xb[HH * WW + gy * WW + gx] - c1;
  float d2 = xb[2 * HH * WW + gy * WW + gx] - c2;
  float s = d0 * d0 + d1 * d1 + d2 * d2;
#pragma unroll
  for (int off = 32; off > 0; off >>= 1) s += __shfl_down(s, off);
  if (lane == 0) wsum[wv] = s;
  __syncthreads();
  if (tid == 0) {
    float tot = wsum[0] + wsum[1] + wsum[2] + wsum[3];
    atomicAdd(out, tot * (1.0f / 6291456.0f));
  }
}

extern "C" void kernel_launch(void* const* d_in, const int* in_sizes, int n_in,
                              void* d_out, int out_size, void* d_ws, size_t ws_size,
                              hipStream_t stream) {
  const float* x = (const float*)d_in[0];
  const int* t = (const int*)d_in[1];
  const float* W1 = (const float*)d_in[2];
  const float* b1 = (const float*)d_in[3];
  const float* tw = (const float*)d_in[4];
  const float* W2 = (const float*)d_in[5];
  const float* b2 = (const float*)d_in[6];
  const float* sched = (const float*)d_in[7];
  float* out = (float*)d_out;
  float* ws = (float*)d_ws;
  unsigned short* z = (unsigned short*)(ws + 3392);

  prep_kernel<<<1, 256, 0, stream>>>(sched, t, W1, b1, tw, W2, ws, out);
  blur_kernel<<<BATCH * CH * 8, 256, 0, stream>>>(x, ws, z);
  dim3 grid(16, 16, BATCH);
  convloss_kernel<<<grid, 256, 0, stream>>>(x, ws, b2, out);
}

// Round 6
// 214.393 us; speedup vs baseline: 1.0930x; 1.0171x over previous
//
#include <hip/hip_runtime.h>

#define BATCH 32
#define CH 3
#define HH 256
#define WW 256
#define KS 29
#define PAD 14
#define NT_F 1000.0f

typedef __attribute__((ext_vector_type(8))) short short8;
typedef __attribute__((ext_vector_type(4))) float f32x4;

union U4 { short8 s8; uint4 u4; };

__device__ inline unsigned short bf16rne(float f) {
  unsigned u = __float_as_uint(f);
  unsigned r = (u + 0x7FFFu + ((u >> 16) & 1u)) >> 16;
  return (unsigned short)r;
}
__device__ inline float bf16tof(unsigned s) {
  return __uint_as_float(s << 16);
}

// ws float layout:
//   gk    [32][32]            @ 0
//   tcond [32][32]            @ 1024
//   w1k   ushort[32][32]      @ 2048  (B-frag-ready conv1 weights, custom k-order)
//   w1g   ushort[32][4]       @ 2560  (conv1 leftover tap (dy2,dx2), ci padded 4)
//   w2b   ushort[3][16][32]   @ 2624  ([dy][n=dx*4+oc][kn], kn = och-interleave perm)
//   z     ushort[32][3][256][256] @ 3392  (bf16 blurred)
//
// conv1 k-order (k = q*8+j, q=k>>3, j=k&7, ci=j&3):
//   q<3 : tap (dy=q,  dx=j>>2, ci)   [ci==3 -> pad 0]
//   q==3: tap (dy=j>>2, dx=2,  ci)
//   second MFMA (K=4 used): j0..3 = (dy=2, dx=2, ci)
// conv2 k-order: kn even -> och=kn/2, kn odd -> och=kn/2+16
//   (lets conv1 store its (col, col+16) pair as one b32 at hs[p][2*col])

// ---------------- prep ----------------
__global__ void prep_kernel(const float* __restrict__ sched,
                            const int* __restrict__ t,
                            const float* __restrict__ W1,
                            const float* __restrict__ b1,
                            const float* __restrict__ tw,
                            const float* __restrict__ W2,
                            float* __restrict__ ws, float* __restrict__ out) {
  int tid = threadIdx.x;
  if (tid == 0) out[0] = 0.0f;
  float* gk = ws;
  float* tcond = ws + 1024;
  unsigned short* w1k = (unsigned short*)(ws + 2048);
  unsigned short* w1g = (unsigned short*)(ws + 2560);
  unsigned short* w2b = (unsigned short*)(ws + 2624);
  if (tid < BATCH) {
    float sigma = sched[t[tid]];
    float inv = 1.0f / sigma;
    float wv[KS];
    float s = 0.0f;
#pragma unroll
    for (int i = 0; i < KS; i++) {
      float xg = (float)(i - PAD) * inv;
      wv[i] = expf(-0.5f * xg * xg);
      s += wv[i];
    }
    float rs = 1.0f / s;
#pragma unroll
    for (int i = 0; i < KS; i++) gk[tid * 32 + i] = wv[i] * rs;
  }
  for (int i = tid; i < 1024; i += 256) {          // w1k
    int o = i >> 5, k = i & 31;
    int q = k >> 3, j = k & 7, ci = j & 3;
    int dy, dx;
    if (q < 3) { dy = q; dx = j >> 2; } else { dy = j >> 2; dx = 2; }
    w1k[i] = (ci < 3) ? bf16rne(W1[o * 27 + ci * 9 + dy * 3 + dx]) : (unsigned short)0;
  }
  for (int i = tid; i < 128; i += 256) {           // w1g
    int o = i >> 2, j = i & 3;
    w1g[i] = (j < 3) ? bf16rne(W1[o * 27 + j * 9 + 8]) : (unsigned short)0;
  }
  for (int i = tid; i < 1536; i += 256) {          // w2b, kn-permuted K
    int dy = i / 512, r = i & 511;
    int n = r >> 5, kn = r & 31;
    int och = (kn >> 1) + ((kn & 1) ? 16 : 0);
    int dx = n >> 2, oc = n & 3;
    w2b[i] = (dx < 3 && oc < 3)
                 ? bf16rne(W2[((oc * 32 + och) * 3 + dy) * 3 + dx])
                 : (unsigned short)0;
  }
  for (int i = tid; i < 1024; i += 256) {          // tcond
    int b = i >> 5, o = i & 31;
    tcond[i] = b1[o] + ((float)t[b] * (1.0f / NT_F)) * tw[o];
  }
}

// ---------------- blur: 32-row groups, register vertical, bf16 out ----------
__global__ __launch_bounds__(256, 3) void blur_kernel(const float* __restrict__ x,
                                                      const float* __restrict__ ws,
                                                      unsigned short* __restrict__ z) {
  __shared__ float vsp[32][288];   // padded cols: idx = col + 16
  int blk = blockIdx.x;            // bc*8 + rg
  int rg = blk & 7;
  int bc = blk >> 3;
  int b = bc / CH;
  int y0 = rg * 32;
  int tid = threadIdx.x;
  const float* xp = x + (size_t)bc * (HH * WW);
  const float* kb = ws + b * 32;   // uniform -> s_load

  float xv[60];
#pragma unroll
  for (int i = 0; i < 60; i++) {
    int gy = y0 - PAD + i;
    gy = (gy < 0) ? -gy : gy;
    gy = (gy >= HH) ? (2 * HH - 2 - gy) : gy;
    xv[i] = xp[gy * WW + tid];
  }
  float acc[32];
#pragma unroll
  for (int yy = 0; yy < 32; yy++) acc[yy] = 0.0f;
#pragma unroll
  for (int kk = 0; kk < KS; kk++) {
    float kv = kb[kk];
#pragma unroll
    for (int yy = 0; yy < 32; yy++) acc[yy] += kv * xv[yy + kk];
  }
#pragma unroll
  for (int yy = 0; yy < 32; yy++) vsp[yy][tid + 16] = acc[yy];
  __syncthreads();
  {
    int row = tid >> 4, i2 = tid & 15;
#pragma unroll
    for (int r2 = 0; r2 < 2; r2++) {
      int rr = row + 16 * r2;
      vsp[rr][i2] = vsp[rr][32 - i2];
      vsp[rr][272 + i2] = vsp[rr][270 - i2];
    }
  }
  __syncthreads();

  size_t zb = (size_t)bc * (HH * WW);
#pragma unroll
  for (int it = 0; it < 8; ++it) {
    int unit = tid + 256 * it;
    int row = unit >> 6, cg = unit & 63;
    float w[36];
#pragma unroll
    for (int i = 0; i < 9; i++)
      *(float4*)&w[4 * i] = *(const float4*)&vsp[row][4 * (cg + i)];
    float o0 = 0, o1 = 0, o2 = 0, o3 = 0;
#pragma unroll
    for (int kk = 0; kk < KS; kk++) {
      float kv = kb[kk];
      o0 += kv * w[2 + kk];
      o1 += kv * w[3 + kk];
      o2 += kv * w[4 + kk];
      o3 += kv * w[5 + kk];
    }
    unsigned u0 = (unsigned)bf16rne(o0) | ((unsigned)bf16rne(o1) << 16);
    unsigned u1 = (unsigned)bf16rne(o2) | ((unsigned)bf16rne(o3) << 16);
    *(uint2*)&z[zb + (size_t)(y0 + row) * WW + 4 * cg] = make_uint2(u0, u1);
  }
}

// ---------------- fused conv1+ReLU+conv2+MSE via bf16 MFMA ----------------
// grid (16,16,B); block 256 = 4 waves; 16x16 output tile
__global__ __launch_bounds__(256, 6) void convloss_kernel(
    const float* __restrict__ x, const float* __restrict__ ws,
    const float* __restrict__ b2g, float* __restrict__ out) {
  __shared__ __align__(16) unsigned short zs4[400 * 4];   // [y*20+x][ci0..2,pad]
  __shared__ __align__(16) unsigned short pool[324 * 36]; // hs, later EsT (23328B)
  __shared__ float wsum[4];
  unsigned short* hs = pool;                 // [p][kn], row 36
  unsigned short* EsT = pool;                // [dy][n][p]: dy*3888 + n*324 + p

  const float* tcond = ws + 1024;
  const unsigned short* w1k = (const unsigned short*)(ws + 2048);
  const unsigned short* w1g = (const unsigned short*)(ws + 2560);
  const unsigned short* w2b = (const unsigned short*)(ws + 2624);
  const unsigned short* zg = (const unsigned short*)(ws + 3392);

  int bx = blockIdx.x, by = blockIdx.y, b = blockIdx.z;
  int tid = threadIdx.x;
  int x0 = bx * 16, y0 = by * 16;
  const unsigned short* zbp = zg + (size_t)b * 3 * HH * WW;

  // stage z tile, channel-interleaved, zero pad slot + zero outside image
#pragma unroll
  for (int r = 0; r < 2; r++) {
    int unit = tid + 256 * r;
    if (unit < 400) {
      int zy = unit / 20, zx = unit - zy * 20;
      int gy = y0 - 2 + zy, gx = x0 - 2 + zx;
      unsigned c0 = 0, c1 = 0, c2 = 0;
      if ((unsigned)gy < (unsigned)HH && (unsigned)gx < (unsigned)WW) {
        int gi = gy * WW + gx;
        c0 = zbp[gi];
        c1 = zbp[HH * WW + gi];
        c2 = zbp[2 * HH * WW + gi];
      }
      *(uint2*)&zs4[unit * 4] = make_uint2(c0 | (c1 << 16), c2);
    }
  }

  int lane = tid & 63;
  int q = lane >> 4;        // quad 0..3
  int col = lane & 15;      // MFMA m/n index
  int wv = tid >> 6;        // wave id

  // B fragments (uniform-stride vector loads from global ws)
  U4 B1a, B1b, B2a, B2b, B2c[3];
  B1a.u4 = *(const uint4*)(w1k + col * 32 + q * 8);
  B1b.u4 = *(const uint4*)(w1k + (col + 16) * 32 + q * 8);
  {
    uint2 ta = *(const uint2*)(w1g + col * 4);
    uint2 tb = *(const uint2*)(w1g + (col + 16) * 4);
    bool q0 = (q == 0);
    B2a.u4 = make_uint4(q0 ? ta.x : 0u, q0 ? ta.y : 0u, 0u, 0u);
    B2b.u4 = make_uint4(q0 ? tb.x : 0u, q0 ? tb.y : 0u, 0u, 0u);
  }
#pragma unroll
  for (int dy = 0; dy < 3; dy++)
    B2c[dy].u4 = *(const uint4*)(w2b + dy * 512 + col * 32 + q * 8);
  float tc0 = tcond[b * 32 + col];
  float tc1 = tcond[b * 32 + 16 + col];

  __syncthreads();   // B1: staging done

  const f32x4 zero4 = {0.0f, 0.0f, 0.0f, 0.0f};
  int dyq = (q < 3) ? q : 0;
  int dxq = (q < 3) ? 0 : 2;
  int strB = (q < 3) ? 4 : 80;   // ushort delta: dx+1 or next row (q3)

  // ---- P1: conv1 -> h (18x18, 32 och); packed b32 stores (kn order) ----
#pragma unroll
  for (int i = 0; i < 6; i++) {
    int g = wv + 4 * i;
    if (g < 21) {                 // wave-uniform guard
      int p = g * 16 + col;
      if (p > 323) p = 323;
      int py = p / 18, px = p - py * 18;
      int a0 = ((py + dyq) * 20 + px + dxq) * 4;
      uint2 lo = *(const uint2*)&zs4[a0];
      uint2 hi = *(const uint2*)&zs4[a0 + strB];
      U4 A1;
      A1.u4 = make_uint4(lo.x, lo.y, hi.x, hi.y);
      uint2 t2 = *(const uint2*)&zs4[((py + 2) * 20 + px + 2) * 4];
      U4 A2;
      bool q0 = (q == 0);
      A2.u4 = make_uint4(q0 ? t2.x : 0u, q0 ? t2.y : 0u, 0u, 0u);
      f32x4 acc0 = __builtin_amdgcn_mfma_f32_16x16x32_bf16(A1.s8, B1a.s8, zero4, 0, 0, 0);
      acc0 = __builtin_amdgcn_mfma_f32_16x16x32_bf16(A2.s8, B2a.s8, acc0, 0, 0, 0);
      f32x4 acc1 = __builtin_amdgcn_mfma_f32_16x16x32_bf16(A1.s8, B1b.s8, zero4, 0, 0, 0);
      acc1 = __builtin_amdgcn_mfma_f32_16x16x32_bf16(A2.s8, B2b.s8, acc1, 0, 0, 0);
      int prow = g * 16 + q * 4;
#pragma unroll
      for (int r = 0; r < 4; r++) {
        int pw = prow + r;
        if (pw < 324) {
          unsigned pk = (unsigned)bf16rne(fmaxf(acc0[r] + tc0, 0.0f)) |
                        ((unsigned)bf16rne(fmaxf(acc1[r] + tc1, 0.0f)) << 16);
          *(unsigned*)&hs[pw * 36 + 2 * col] = pk;
        }
      }
    }
  }
  __syncthreads();   // B2: h complete

  // ---- preload conv2 A-fragments (kn order matches w2b) ----
  U4 A2h[6];
#pragma unroll
  for (int i = 0; i < 6; i++) {
    int g = wv + 4 * i;
    int p = g * 16 + col;
    if (p > 323) p = 323;
    uint2 u0 = *(const uint2*)&hs[p * 36 + q * 8];
    uint2 u1 = *(const uint2*)&hs[p * 36 + q * 8 + 4];
    A2h[i].u4 = make_uint4(u0.x, u0.y, u1.x, u1.y);
  }
  __syncthreads();   // B3: hs reads done, pool may be overwritten as EsT

  // ---- conv2 partials: all 3 dy planes in one pass ----
#pragma unroll
  for (int dy = 0; dy < 3; dy++) {
#pragma unroll
    for (int i = 0; i < 6; i++) {
      int g = wv + 4 * i;
      if (g < 21) {               // wave-uniform guard
        f32x4 e = __builtin_amdgcn_mfma_f32_16x16x32_bf16(A2h[i].s8, B2c[dy].s8, zero4, 0, 0, 0);
        int prow = g * 16 + q * 4;
        if (col < 12 && prow < 324) {
          unsigned v0 = (unsigned)bf16rne(e[0]) | ((unsigned)bf16rne(e[1]) << 16);
          unsigned v1 = (unsigned)bf16rne(e[2]) | ((unsigned)bf16rne(e[3]) << 16);
          *(uint2*)&EsT[dy * 3888 + col * 324 + prow] = make_uint2(v0, v1);
        }
      }
    }
  }
  __syncthreads();   // B4: E planes complete

  // ---- gather + MSE ----
  int ty = tid >> 4, tx = tid & 15;
  float c0 = b2g[0], c1 = b2g[1], c2 = b2g[2];
#pragma unroll
  for (int dy = 0; dy < 3; dy++) {
    int pr = (ty + dy) * 18 + tx;
#pragma unroll
    for (int dx = 0; dx < 3; dx++) {
      int pp = pr + dx;
      c0 += bf16tof(EsT[dy * 3888 + (dx * 4 + 0) * 324 + pp]);
      c1 += bf16tof(EsT[dy * 3888 + (dx * 4 + 1) * 324 + pp]);
      c2 += bf16tof(EsT[dy * 3888 + (dx * 4 + 2) * 324 + pp]);
    }
  }

  int gy = y0 + ty, gx = x0 + tx;
  const float* xb = x + (size_t)b * 3 * HH * WW;
  float d0 = xb[gy * WW + gx] - c0;
  float d1 = xb[HH * WW + gy * WW + gx] - c1;
  float d2 = xb[2 * HH * WW + gy * WW + gx] - c2;
  float s = d0 * d0 + d1 * d1 + d2 * d2;
#pragma unroll
  for (int off = 32; off > 0; off >>= 1) s += __shfl_down(s, off);
  if (lane == 0) wsum[wv] = s;
  __syncthreads();   // B5
  if (tid == 0) {
    float tot = wsum[0] + wsum[1] + wsum[2] + wsum[3];
    atomicAdd(out, tot * (1.0f / 6291456.0f));
  }
}

extern "C" void kernel_launch(void* const* d_in, const int* in_sizes, int n_in,
                              void* d_out, int out_size, void* d_ws, size_t ws_size,
                              hipStream_t stream) {
  const float* x = (const float*)d_in[0];
  const int* t = (const int*)d_in[1];
  const float* W1 = (const float*)d_in[2];
  const float* b1 = (const float*)d_in[3];
  const float* tw = (const float*)d_in[4];
  const float* W2 = (const float*)d_in[5];
  const float* b2 = (const float*)d_in[6];
  const float* sched = (const float*)d_in[7];
  float* out = (float*)d_out;
  float* ws = (float*)d_ws;
  unsigned short* z = (unsigned short*)(ws + 3392);

  prep_kernel<<<1, 256, 0, stream>>>(sched, t, W1, b1, tw, W2, ws, out);
  blur_kernel<<<BATCH * CH * 8, 256, 0, stream>>>(x, ws, z);
  dim3 grid(16, 16, BATCH);
  convloss_kernel<<<grid, 256, 0, stream>>>(x, ws, b2, out);
}

// Round 7
// 213.898 us; speedup vs baseline: 1.0955x; 1.0023x over previous
//
#include <hip/hip_runtime.h>
#include <hip/hip_bf16.h>

#define BATCH 32
#define CH 3
#define HH 256
#define WW 256
#define KS 29
#define PAD 14
#define NT_F 1000.0f

typedef __attribute__((ext_vector_type(8))) short short8;
typedef __attribute__((ext_vector_type(4))) float f32x4;

union U4 { short8 s8; uint4 u4; };

__device__ inline unsigned short bf16rne(float f) {
  unsigned u = __float_as_uint(f);
  unsigned r = (u + 0x7FFFu + ((u >> 16) & 1u)) >> 16;
  return (unsigned short)r;
}
__device__ inline unsigned pk_bf16(float a, float b) {
  union { __hip_bfloat162 h2; unsigned u; } cv;
  cv.h2 = __float22bfloat162_rn(make_float2(a, b));
  return cv.u;
}

// ws float layout:
//   gk    [32][32]            @ 0
//   tcond [32][32]            @ 1024
//   w1k   ushort[32][32]      @ 2048  (B-frag conv1 weights, custom k-order)
//   w1g   ushort[32][4]       @ 2560  (conv1 leftover tap (dy2,dx2), ci pad 4)
//   w2c   ushort[9][16][32]   @ 2624  ([tap][n=oc(16)][kn], kn = och-interleave)
//   z     ushort[32][3][256][256] @ 4928  (bf16 blurred)
//
// conv1 k-order (k=q*8+j, ci=j&3): q<3: (dy=q,dx=j>>2,ci); q3: (dy=j>>2,dx=2,ci)
//   second MFMA (K=4): j0..3 = (dy=2,dx=2,ci)
// kn interleave: kn even -> och=kn/2, odd -> och=kn/2+16
//   (conv1 stores its (col, col+16) h pair as one b32 at hs[p][2*col])

// ---------------- prep ----------------
__global__ void prep_kernel(const float* __restrict__ sched,
                            const int* __restrict__ t,
                            const float* __restrict__ W1,
                            const float* __restrict__ b1,
                            const float* __restrict__ tw,
                            const float* __restrict__ W2,
                            float* __restrict__ ws, float* __restrict__ out) {
  int tid = threadIdx.x;
  if (tid == 0) out[0] = 0.0f;
  float* gk = ws;
  float* tcond = ws + 1024;
  unsigned short* w1k = (unsigned short*)(ws + 2048);
  unsigned short* w1g = (unsigned short*)(ws + 2560);
  unsigned short* w2c = (unsigned short*)(ws + 2624);
  if (tid < BATCH) {
    float sigma = sched[t[tid]];
    float inv = 1.0f / sigma;
    float wv[KS];
    float s = 0.0f;
#pragma unroll
    for (int i = 0; i < KS; i++) {
      float xg = (float)(i - PAD) * inv;
      wv[i] = expf(-0.5f * xg * xg);
      s += wv[i];
    }
    float rs = 1.0f / s;
#pragma unroll
    for (int i = 0; i < KS; i++) gk[tid * 32 + i] = wv[i] * rs;
  }
  for (int i = tid; i < 1024; i += 256) {          // w1k
    int o = i >> 5, k = i & 31;
    int q = k >> 3, j = k & 7, ci = j & 3;
    int dy, dx;
    if (q < 3) { dy = q; dx = j >> 2; } else { dy = j >> 2; dx = 2; }
    w1k[i] = (ci < 3) ? bf16rne(W1[o * 27 + ci * 9 + dy * 3 + dx]) : (unsigned short)0;
  }
  for (int i = tid; i < 128; i += 256) {           // w1g
    int o = i >> 2, j = i & 3;
    w1g[i] = (j < 3) ? bf16rne(W1[o * 27 + j * 9 + 8]) : (unsigned short)0;
  }
  for (int i = tid; i < 4608; i += 256) {          // w2c [tap][oc(16)][kn(32)]
    int tap = i >> 9, r = i & 511;
    int n = r >> 5, kn = r & 31;
    int och = (kn >> 1) + ((kn & 1) ? 16 : 0);
    int dy = tap / 3, dx = tap - dy * 3;
    w2c[i] = (n < 3) ? bf16rne(W2[((n * 32 + och) * 3 + dy) * 3 + dx])
                     : (unsigned short)0;
  }
  for (int i = tid; i < 1024; i += 256) {          // tcond
    int b = i >> 5, o = i & 31;
    tcond[i] = b1[o] + ((float)t[b] * (1.0f / NT_F)) * tw[o];
  }
}

// ---------------- blur: 32-row groups, register vertical, bf16 out ----------
__global__ __launch_bounds__(256, 3) void blur_kernel(const float* __restrict__ x,
                                                      const float* __restrict__ ws,
                                                      unsigned short* __restrict__ z) {
  __shared__ float vsp[32][288];   // padded cols: idx = col + 16
  int blk = blockIdx.x;            // bc*8 + rg
  int rg = blk & 7;
  int bc = blk >> 3;
  int b = bc / CH;
  int y0 = rg * 32;
  int tid = threadIdx.x;
  const float* xp = x + (size_t)bc * (HH * WW);
  const float* kb = ws + b * 32;   // uniform -> s_load

  float xv[60];
#pragma unroll
  for (int i = 0; i < 60; i++) {
    int gy = y0 - PAD + i;
    gy = (gy < 0) ? -gy : gy;
    gy = (gy >= HH) ? (2 * HH - 2 - gy) : gy;
    xv[i] = xp[gy * WW + tid];
  }
  float acc[32];
#pragma unroll
  for (int yy = 0; yy < 32; yy++) acc[yy] = 0.0f;
#pragma unroll
  for (int kk = 0; kk < KS; kk++) {
    float kv = kb[kk];
#pragma unroll
    for (int yy = 0; yy < 32; yy++) acc[yy] += kv * xv[yy + kk];
  }
#pragma unroll
  for (int yy = 0; yy < 32; yy++) vsp[yy][tid + 16] = acc[yy];
  __syncthreads();
  {
    int row = tid >> 4, i2 = tid & 15;
#pragma unroll
    for (int r2 = 0; r2 < 2; r2++) {
      int rr = row + 16 * r2;
      vsp[rr][i2] = vsp[rr][32 - i2];
      vsp[rr][272 + i2] = vsp[rr][270 - i2];
    }
  }
  __syncthreads();

  size_t zb = (size_t)bc * (HH * WW);
#pragma unroll
  for (int it = 0; it < 8; ++it) {
    int unit = tid + 256 * it;
    int row = unit >> 6, cg = unit & 63;
    float w[36];
#pragma unroll
    for (int i = 0; i < 9; i++)
      *(float4*)&w[4 * i] = *(const float4*)&vsp[row][4 * (cg + i)];
    float o0 = 0, o1 = 0, o2 = 0, o3 = 0;
#pragma unroll
    for (int kk = 0; kk < KS; kk++) {
      float kv = kb[kk];
      o0 += kv * w[2 + kk];
      o1 += kv * w[3 + kk];
      o2 += kv * w[4 + kk];
      o3 += kv * w[5 + kk];
    }
    unsigned u0 = pk_bf16(o0, o1);
    unsigned u1 = pk_bf16(o2, o3);
    *(uint2*)&z[zb + (size_t)(y0 + row) * WW + 4 * cg] = make_uint2(u0, u1);
  }
}

// ---------------- fused conv1+ReLU+conv2+MSE via bf16 MFMA ----------------
// grid (16,16,B); block 256 = 4 waves; 16x16 output tile; 3 barriers total
__global__ __launch_bounds__(256, 5) void convloss_kernel(
    const float* __restrict__ x, const float* __restrict__ ws,
    const float* __restrict__ b2g, float* __restrict__ out) {
  __shared__ __align__(16) unsigned short zs4[400 * 4];   // [y*20+x][ci0..2,pad]
  __shared__ __align__(16) unsigned short hs[324 * 40];   // [p18][kn(32)+pad8]
  __shared__ float wsum[4];

  const float* tcond = ws + 1024;
  const unsigned short* w1k = (const unsigned short*)(ws + 2048);
  const unsigned short* w1g = (const unsigned short*)(ws + 2560);
  const unsigned short* w2c = (const unsigned short*)(ws + 2624);
  const unsigned short* zg = (const unsigned short*)(ws + 4928);

  int bx = blockIdx.x, by = blockIdx.y, b = blockIdx.z;
  int tid = threadIdx.x;
  int x0 = bx * 16, y0 = by * 16;
  const unsigned short* zbp = zg + (size_t)b * 3 * HH * WW;

  int lane = tid & 63;
  int q = lane >> 4;        // quad 0..3
  int col = lane & 15;      // MFMA m/n index
  int wv = tid >> 6;        // wave id

  // stage z tile, channel-interleaved, zero pad slot + zero outside image
#pragma unroll
  for (int r = 0; r < 2; r++) {
    int unit = tid + 256 * r;
    if (unit < 400) {
      int zy = unit / 20, zx = unit - zy * 20;
      int gy = y0 - 2 + zy, gx = x0 - 2 + zx;
      unsigned c0 = 0, c1 = 0, c2 = 0;
      if ((unsigned)gy < (unsigned)HH && (unsigned)gx < (unsigned)WW) {
        int gi = gy * WW + gx;
        c0 = zbp[gi];
        c1 = zbp[HH * WW + gi];
        c2 = zbp[2 * HH * WW + gi];
      }
      *(uint2*)&zs4[unit * 4] = make_uint2(c0 | (c1 << 16), c2);
    }
  }

  // prefetch MSE x reads (independent of everything; consumed at the end)
  const float* xb = x + (size_t)b * 3 * HH * WW;
  int colc = (col < 3) ? col : 0;
  float4 xpre[4];
#pragma unroll
  for (int i = 0; i < 4; i++) {
    int g2 = wv * 4 + i;
    xpre[i] = *(const float4*)&xb[colc * (HH * WW) + (y0 + g2) * WW + x0 + q * 4];
  }

  // conv1 B fragments (uniform-stride vector loads from global ws)
  U4 B1a, B1b, B2a, B2b;
  B1a.u4 = *(const uint4*)(w1k + col * 32 + q * 8);
  B1b.u4 = *(const uint4*)(w1k + (col + 16) * 32 + q * 8);
  {
    uint2 ta = *(const uint2*)(w1g + col * 4);
    uint2 tb = *(const uint2*)(w1g + (col + 16) * 4);
    bool q0 = (q == 0);
    B2a.u4 = make_uint4(q0 ? ta.x : 0u, q0 ? ta.y : 0u, 0u, 0u);
    B2b.u4 = make_uint4(q0 ? tb.x : 0u, q0 ? tb.y : 0u, 0u, 0u);
  }
  float tc0 = tcond[b * 32 + col];
  float tc1 = tcond[b * 32 + 16 + col];
  float b2v = b2g[colc];

  __syncthreads();   // B1: z staged

  const f32x4 zero4 = {0.0f, 0.0f, 0.0f, 0.0f};
  int dyq = (q < 3) ? q : 0;
  int dxq = (q < 3) ? 0 : 2;
  int strB = (q < 3) ? 4 : 80;   // ushort delta: dx+1 or next row (q3)

  // ---- P1: conv1 -> h (18x18, 32 och); packed b32 stores (kn order) ----
#pragma unroll
  for (int i = 0; i < 6; i++) {
    int g = wv + 4 * i;
    if (g < 21) {                 // wave-uniform guard
      int p = g * 16 + col;
      if (p > 323) p = 323;
      int py = p / 18, px = p - py * 18;
      int a0 = ((py + dyq) * 20 + px + dxq) * 4;
      uint2 lo = *(const uint2*)&zs4[a0];
      uint2 hi = *(const uint2*)&zs4[a0 + strB];
      U4 A1;
      A1.u4 = make_uint4(lo.x, lo.y, hi.x, hi.y);
      uint2 t2 = *(const uint2*)&zs4[((py + 2) * 20 + px + 2) * 4];
      U4 A2;
      bool q0 = (q == 0);
      A2.u4 = make_uint4(q0 ? t2.x : 0u, q0 ? t2.y : 0u, 0u, 0u);
      f32x4 acc0 = __builtin_amdgcn_mfma_f32_16x16x32_bf16(A1.s8, B1a.s8, zero4, 0, 0, 0);
      acc0 = __builtin_amdgcn_mfma_f32_16x16x32_bf16(A2.s8, B2a.s8, acc0, 0, 0, 0);
      f32x4 acc1 = __builtin_amdgcn_mfma_f32_16x16x32_bf16(A1.s8, B1b.s8, zero4, 0, 0, 0);
      acc1 = __builtin_amdgcn_mfma_f32_16x16x32_bf16(A2.s8, B2b.s8, acc1, 0, 0, 0);
      int prow = g * 16 + q * 4;
#pragma unroll
      for (int r = 0; r < 4; r++) {
        int pw = prow + r;
        if (pw < 324) {
          unsigned pk = pk_bf16(fmaxf(acc0[r] + tc0, 0.0f),
                                fmaxf(acc1[r] + tc1, 0.0f));
          *(unsigned*)&hs[pw * 40 + 2 * col] = pk;
        }
      }
    }
  }
  __syncthreads();   // B2: h complete

  // ---- conv2 as direct implicit GEMM: 9 accumulating MFMAs per out-row ----
  // wave handles out rows oy = wv*4 + i (i=0..3); A: m=ox(col), k=kn(q*8+j)
  f32x4 dacc[4];
#pragma unroll
  for (int i = 0; i < 4; i++) dacc[i] = zero4;
#pragma unroll
  for (int tap = 0; tap < 9; tap++) {
    const int dy = tap / 3, dx = tap - (tap / 3) * 3;
    U4 Bt;
    Bt.u4 = *(const uint4*)(w2c + tap * 512 + col * 32 + q * 8);
#pragma unroll
    for (int i = 0; i < 4; i++) {
      int g2 = wv * 4 + i;
      int p18 = (g2 + dy) * 18 + (col + dx);
      U4 A;
      A.u4 = *(const uint4*)&hs[p18 * 40 + q * 8];   // ds_read_b128
      dacc[i] = __builtin_amdgcn_mfma_f32_16x16x32_bf16(A.s8, Bt.s8, dacc[i], 0, 0, 0);
    }
  }

  // ---- MSE straight from D fragments (oc=col<3, ox=q*4+r, oy=g2) ----
  float s = 0.0f;
  if (col < 3) {
#pragma unroll
    for (int i = 0; i < 4; i++) {
      float4 xv = xpre[i];
      float d0 = xv.x - (dacc[i][0] + b2v);
      float d1 = xv.y - (dacc[i][1] + b2v);
      float d2 = xv.z - (dacc[i][2] + b2v);
      float d3 = xv.w - (dacc[i][3] + b2v);
      s += d0 * d0 + d1 * d1 + d2 * d2 + d3 * d3;
    }
  }
#pragma unroll
  for (int off = 32; off > 0; off >>= 1) s += __shfl_down(s, off);
  if (lane == 0) wsum[wv] = s;
  __syncthreads();   // B3
  if (tid == 0) {
    float tot = wsum[0] + wsum[1] + wsum[2] + wsum[3];
    atomicAdd(out, tot * (1.0f / 6291456.0f));
  }
}

extern "C" void kernel_launch(void* const* d_in, const int* in_sizes, int n_in,
                              void* d_out, int out_size, void* d_ws, size_t ws_size,
                              hipStream_t stream) {
  const float* x = (const float*)d_in[0];
  const int* t = (const int*)d_in[1];
  const float* W1 = (const float*)d_in[2];
  const float* b1 = (const float*)d_in[3];
  const float* tw = (const float*)d_in[4];
  const float* W2 = (const float*)d_in[5];
  const float* b2 = (const float*)d_in[6];
  const float* sched = (const float*)d_in[7];
  float* out = (float*)d_out;
  float* ws = (float*)d_ws;
  unsigned short* z = (unsigned short*)(ws + 4928);

  prep_kernel<<<1, 256, 0, stream>>>(sched, t, W1, b1, tw, W2, ws, out);
  blur_kernel<<<BATCH * CH * 8, 256, 0, stream>>>(x, ws, z);
  dim3 grid(16, 16, BATCH);
  convloss_kernel<<<grid, 256, 0, stream>>>(x, ws, b2, out);
}

// Round 8
// 146.765 us; speedup vs baseline: 1.5966x; 1.4574x over previous
//
#include <hip/hip_runtime.h>
#include <hip/hip_bf16.h>

#define BATCH 32
#define CH 3
#define HH 256
#define WW 256
#define KS 29
#define PAD 14
#define NT_F 1000.0f

typedef __attribute__((ext_vector_type(8))) short short8;
typedef __attribute__((ext_vector_type(4))) float f32x4;

union U4 { short8 s8; uint4 u4; };

__device__ inline unsigned short bf16rne(float f) {
  unsigned u = __float_as_uint(f);
  unsigned r = (u + 0x7FFFu + ((u >> 16) & 1u)) >> 16;
  return (unsigned short)r;
}
__device__ inline unsigned pk_bf16(float a, float b) {
  union { __hip_bfloat162 h2; unsigned u; } cv;
  cv.h2 = __float22bfloat162_rn(make_float2(a, b));
  return cv.u;
}

// ws float layout:
//   gk    [32][32]            @ 0
//   tcond [32][32]            @ 1024
//   w1k   ushort[32][32]      @ 2048  (B-frag conv1 weights, custom k-order)
//   w1g   ushort[32][4]       @ 2560  (conv1 leftover tap (dy2,dx2), ci pad 4)
//   w2c   ushort[9][16][32]   @ 2624  ([tap][n=oc(16)][kn], kn = och-interleave)
//   z     ushort[32][3][256][256] @ 4928  (bf16 blurred)
//   partial float[8192]       @ 3150656  (per-block MSE partials, no atomics)
//
// conv1 k-order (k=q*8+j, ci=j&3): q<3: (dy=q,dx=j>>2,ci); q3: (dy=j>>2,dx=2,ci)
//   second MFMA (K=4): j0..3 = (dy=2,dx=2,ci)
// kn interleave: kn even -> och=kn/2, odd -> och=kn/2+16

#define PARTIAL_OFF 3150656

// ---------------- prep ----------------
__global__ void prep_kernel(const float* __restrict__ sched,
                            const int* __restrict__ t,
                            const float* __restrict__ W1,
                            const float* __restrict__ b1,
                            const float* __restrict__ tw,
                            const float* __restrict__ W2,
                            float* __restrict__ ws) {
  int tid = threadIdx.x;
  float* gk = ws;
  float* tcond = ws + 1024;
  unsigned short* w1k = (unsigned short*)(ws + 2048);
  unsigned short* w1g = (unsigned short*)(ws + 2560);
  unsigned short* w2c = (unsigned short*)(ws + 2624);
  if (tid < BATCH) {
    float sigma = sched[t[tid]];
    float inv = 1.0f / sigma;
    float wv[KS];
    float s = 0.0f;
#pragma unroll
    for (int i = 0; i < KS; i++) {
      float xg = (float)(i - PAD) * inv;
      wv[i] = expf(-0.5f * xg * xg);
      s += wv[i];
    }
    float rs = 1.0f / s;
#pragma unroll
    for (int i = 0; i < KS; i++) gk[tid * 32 + i] = wv[i] * rs;
  }
  for (int i = tid; i < 1024; i += 256) {          // w1k
    int o = i >> 5, k = i & 31;
    int q = k >> 3, j = k & 7, ci = j & 3;
    int dy, dx;
    if (q < 3) { dy = q; dx = j >> 2; } else { dy = j >> 2; dx = 2; }
    w1k[i] = (ci < 3) ? bf16rne(W1[o * 27 + ci * 9 + dy * 3 + dx]) : (unsigned short)0;
  }
  for (int i = tid; i < 128; i += 256) {           // w1g
    int o = i >> 2, j = i & 3;
    w1g[i] = (j < 3) ? bf16rne(W1[o * 27 + j * 9 + 8]) : (unsigned short)0;
  }
  for (int i = tid; i < 4608; i += 256) {          // w2c [tap][oc(16)][kn(32)]
    int tap = i >> 9, r = i & 511;
    int n = r >> 5, kn = r & 31;
    int och = (kn >> 1) + ((kn & 1) ? 16 : 0);
    int dy = tap / 3, dx = tap - dy * 3;
    w2c[i] = (n < 3) ? bf16rne(W2[((n * 32 + och) * 3 + dy) * 3 + dx])
                     : (unsigned short)0;
  }
  for (int i = tid; i < 1024; i += 256) {          // tcond
    int b = i >> 5, o = i & 31;
    tcond[i] = b1[o] + ((float)t[b] * (1.0f / NT_F)) * tw[o];
  }
}

// ---------------- blur: 32-row groups, register vertical, bf16 out ----------
__global__ __launch_bounds__(256, 3) void blur_kernel(const float* __restrict__ x,
                                                      const float* __restrict__ ws,
                                                      unsigned short* __restrict__ z) {
  __shared__ float vsp[32][288];   // padded cols: idx = col + 16
  int blk = blockIdx.x;            // bc*8 + rg
  int rg = blk & 7;
  int bc = blk >> 3;
  int b = bc / CH;
  int y0 = rg * 32;
  int tid = threadIdx.x;
  const float* xp = x + (size_t)bc * (HH * WW);
  const float* kb = ws + b * 32;   // uniform -> s_load

  float xv[60];
#pragma unroll
  for (int i = 0; i < 60; i++) {
    int gy = y0 - PAD + i;
    gy = (gy < 0) ? -gy : gy;
    gy = (gy >= HH) ? (2 * HH - 2 - gy) : gy;
    xv[i] = xp[gy * WW + tid];
  }
  float acc[32];
#pragma unroll
  for (int yy = 0; yy < 32; yy++) acc[yy] = 0.0f;
#pragma unroll
  for (int kk = 0; kk < KS; kk++) {
    float kv = kb[kk];
#pragma unroll
    for (int yy = 0; yy < 32; yy++) acc[yy] += kv * xv[yy + kk];
  }
#pragma unroll
  for (int yy = 0; yy < 32; yy++) vsp[yy][tid + 16] = acc[yy];
  __syncthreads();
  {
    int row = tid >> 4, i2 = tid & 15;
#pragma unroll
    for (int r2 = 0; r2 < 2; r2++) {
      int rr = row + 16 * r2;
      vsp[rr][i2] = vsp[rr][32 - i2];
      vsp[rr][272 + i2] = vsp[rr][270 - i2];
    }
  }
  __syncthreads();

  size_t zb = (size_t)bc * (HH * WW);
#pragma unroll
  for (int it = 0; it < 8; ++it) {
    int unit = tid + 256 * it;
    int row = unit >> 6, cg = unit & 63;
    float w[36];
#pragma unroll
    for (int i = 0; i < 9; i++)
      *(float4*)&w[4 * i] = *(const float4*)&vsp[row][4 * (cg + i)];
    float o0 = 0, o1 = 0, o2 = 0, o3 = 0;
#pragma unroll
    for (int kk = 0; kk < KS; kk++) {
      float kv = kb[kk];
      o0 += kv * w[2 + kk];
      o1 += kv * w[3 + kk];
      o2 += kv * w[4 + kk];
      o3 += kv * w[5 + kk];
    }
    unsigned u0 = pk_bf16(o0, o1);
    unsigned u1 = pk_bf16(o2, o3);
    *(uint2*)&z[zb + (size_t)(y0 + row) * WW + 4 * cg] = make_uint2(u0, u1);
  }
}

// ---------------- fused conv1+ReLU+conv2+MSE via bf16 MFMA ----------------
// grid (16,16,B); block 256 = 4 waves; per-block partial -> NO global atomic
__global__ __launch_bounds__(256, 5) void convloss_kernel(
    const float* __restrict__ x, const float* __restrict__ ws,
    const float* __restrict__ b2g, float* __restrict__ partial) {
  __shared__ __align__(16) unsigned short zs4[400 * 4];   // [y*20+x][ci0..2,pad]
  __shared__ __align__(16) unsigned short hs[324 * 40];   // [p18][kn(32)+pad8]
  __shared__ float wsum[4];

  const float* tcond = ws + 1024;
  const unsigned short* w1k = (const unsigned short*)(ws + 2048);
  const unsigned short* w1g = (const unsigned short*)(ws + 2560);
  const unsigned short* w2c = (const unsigned short*)(ws + 2624);
  const unsigned short* zg = (const unsigned short*)(ws + 4928);

  int bx = blockIdx.x, by = blockIdx.y, b = blockIdx.z;
  int tid = threadIdx.x;
  int x0 = bx * 16, y0 = by * 16;
  const unsigned short* zbp = zg + (size_t)b * 3 * HH * WW;

  int lane = tid & 63;
  int q = lane >> 4;        // quad 0..3
  int col = lane & 15;      // MFMA m/n index
  int wv = tid >> 6;        // wave id

  // stage z tile, channel-interleaved, zero pad slot + zero outside image
#pragma unroll
  for (int r = 0; r < 2; r++) {
    int unit = tid + 256 * r;
    if (unit < 400) {
      int zy = unit / 20, zx = unit - zy * 20;
      int gy = y0 - 2 + zy, gx = x0 - 2 + zx;
      unsigned c0 = 0, c1 = 0, c2 = 0;
      if ((unsigned)gy < (unsigned)HH && (unsigned)gx < (unsigned)WW) {
        int gi = gy * WW + gx;
        c0 = zbp[gi];
        c1 = zbp[HH * WW + gi];
        c2 = zbp[2 * HH * WW + gi];
      }
      *(uint2*)&zs4[unit * 4] = make_uint2(c0 | (c1 << 16), c2);
    }
  }

  // prefetch MSE x reads (independent of everything; consumed at the end)
  const float* xb = x + (size_t)b * 3 * HH * WW;
  int colc = (col < 3) ? col : 0;
  float4 xpre[4];
#pragma unroll
  for (int i = 0; i < 4; i++) {
    int g2 = wv * 4 + i;
    xpre[i] = *(const float4*)&xb[colc * (HH * WW) + (y0 + g2) * WW + x0 + q * 4];
  }

  // conv1 B fragments (uniform-stride vector loads from global ws)
  U4 B1a, B1b, B2a, B2b;
  B1a.u4 = *(const uint4*)(w1k + col * 32 + q * 8);
  B1b.u4 = *(const uint4*)(w1k + (col + 16) * 32 + q * 8);
  {
    uint2 ta = *(const uint2*)(w1g + col * 4);
    uint2 tb = *(const uint2*)(w1g + (col + 16) * 4);
    bool q0 = (q == 0);
    B2a.u4 = make_uint4(q0 ? ta.x : 0u, q0 ? ta.y : 0u, 0u, 0u);
    B2b.u4 = make_uint4(q0 ? tb.x : 0u, q0 ? tb.y : 0u, 0u, 0u);
  }
  float tc0 = tcond[b * 32 + col];
  float tc1 = tcond[b * 32 + 16 + col];
  float b2v = b2g[colc];

  __syncthreads();   // B1: z staged

  const f32x4 zero4 = {0.0f, 0.0f, 0.0f, 0.0f};
  int dyq = (q < 3) ? q : 0;
  int dxq = (q < 3) ? 0 : 2;
  int strB = (q < 3) ? 4 : 80;   // ushort delta: dx+1 or next row (q3)

  // ---- P1: conv1 -> h (18x18, 32 och); packed b32 stores (kn order) ----
#pragma unroll
  for (int i = 0; i < 6; i++) {
    int g = wv + 4 * i;
    if (g < 21) {                 // wave-uniform guard
      int p = g * 16 + col;
      if (p > 323) p = 323;
      int py = p / 18, px = p - py * 18;
      int a0 = ((py + dyq) * 20 + px + dxq) * 4;
      uint2 lo = *(const uint2*)&zs4[a0];
      uint2 hi = *(const uint2*)&zs4[a0 + strB];
      U4 A1;
      A1.u4 = make_uint4(lo.x, lo.y, hi.x, hi.y);
      uint2 t2 = *(const uint2*)&zs4[((py + 2) * 20 + px + 2) * 4];
      U4 A2;
      bool q0 = (q == 0);
      A2.u4 = make_uint4(q0 ? t2.x : 0u, q0 ? t2.y : 0u, 0u, 0u);
      f32x4 acc0 = __builtin_amdgcn_mfma_f32_16x16x32_bf16(A1.s8, B1a.s8, zero4, 0, 0, 0);
      acc0 = __builtin_amdgcn_mfma_f32_16x16x32_bf16(A2.s8, B2a.s8, acc0, 0, 0, 0);
      f32x4 acc1 = __builtin_amdgcn_mfma_f32_16x16x32_bf16(A1.s8, B1b.s8, zero4, 0, 0, 0);
      acc1 = __builtin_amdgcn_mfma_f32_16x16x32_bf16(A2.s8, B2b.s8, acc1, 0, 0, 0);
      int prow = g * 16 + q * 4;
#pragma unroll
      for (int r = 0; r < 4; r++) {
        int pw = prow + r;
        if (pw < 324) {
          unsigned pk = pk_bf16(fmaxf(acc0[r] + tc0, 0.0f),
                                fmaxf(acc1[r] + tc1, 0.0f));
          *(unsigned*)&hs[pw * 40 + 2 * col] = pk;
        }
      }
    }
  }
  __syncthreads();   // B2: h complete

  // ---- conv2 as direct implicit GEMM: 9 accumulating MFMAs per out-row ----
  f32x4 dacc[4];
#pragma unroll
  for (int i = 0; i < 4; i++) dacc[i] = zero4;
#pragma unroll
  for (int tap = 0; tap < 9; tap++) {
    const int dy = tap / 3, dx = tap - (tap / 3) * 3;
    U4 Bt;
    Bt.u4 = *(const uint4*)(w2c + tap * 512 + col * 32 + q * 8);
#pragma unroll
    for (int i = 0; i < 4; i++) {
      int g2 = wv * 4 + i;
      int p18 = (g2 + dy) * 18 + (col + dx);
      U4 A;
      A.u4 = *(const uint4*)&hs[p18 * 40 + q * 8];   // ds_read_b128
      dacc[i] = __builtin_amdgcn_mfma_f32_16x16x32_bf16(A.s8, Bt.s8, dacc[i], 0, 0, 0);
    }
  }

  // ---- MSE partial from D fragments (oc=col<3, ox=q*4+r, oy=g2) ----
  float s = 0.0f;
  if (col < 3) {
#pragma unroll
    for (int i = 0; i < 4; i++) {
      float4 xv = xpre[i];
      float d0 = xv.x - (dacc[i][0] + b2v);
      float d1 = xv.y - (dacc[i][1] + b2v);
      float d2 = xv.z - (dacc[i][2] + b2v);
      float d3 = xv.w - (dacc[i][3] + b2v);
      s += d0 * d0 + d1 * d1 + d2 * d2 + d3 * d3;
    }
  }
#pragma unroll
  for (int off = 32; off > 0; off >>= 1) s += __shfl_down(s, off);
  if (lane == 0) wsum[wv] = s;
  __syncthreads();   // B3
  if (tid == 0) {
    // contention-free per-block store; reduced by reduce_kernel
    int bid = (b * 16 + by) * 16 + bx;
    partial[bid] = wsum[0] + wsum[1] + wsum[2] + wsum[3];
  }
}

// ---------------- final reduce: 8192 partials -> out[0] ----------------
__global__ __launch_bounds__(256) void reduce_kernel(const float* __restrict__ partial,
                                                     float* __restrict__ out) {
  __shared__ float wsum[4];
  int tid = threadIdx.x;
  float s = 0.0f;
#pragma unroll
  for (int i = 0; i < 8; i++) {
    float4 v = *(const float4*)&partial[(tid + 256 * i) * 4];
    s += v.x + v.y + v.z + v.w;
  }
#pragma unroll
  for (int off = 32; off > 0; off >>= 1) s += __shfl_down(s, off);
  if ((tid & 63) == 0) wsum[tid >> 6] = s;
  __syncthreads();
  if (tid == 0)
    out[0] = (wsum[0] + wsum[1] + wsum[2] + wsum[3]) * (1.0f / 6291456.0f);
}

extern "C" void kernel_launch(void* const* d_in, const int* in_sizes, int n_in,
                              void* d_out, int out_size, void* d_ws, size_t ws_size,
                              hipStream_t stream) {
  const float* x = (const float*)d_in[0];
  const int* t = (const int*)d_in[1];
  const float* W1 = (const float*)d_in[2];
  const float* b1 = (const float*)d_in[3];
  const float* tw = (const float*)d_in[4];
  const float* W2 = (const float*)d_in[5];
  const float* b2 = (const float*)d_in[6];
  const float* sched = (const float*)d_in[7];
  float* out = (float*)d_out;
  float* ws = (float*)d_ws;
  unsigned short* z = (unsigned short*)(ws + 4928);
  float* partial = ws + PARTIAL_OFF;

  prep_kernel<<<1, 256, 0, stream>>>(sched, t, W1, b1, tw, W2, ws);
  blur_kernel<<<BATCH * CH * 8, 256, 0, stream>>>(x, ws, z);
  dim3 grid(16, 16, BATCH);
  convloss_kernel<<<grid, 256, 0, stream>>>(x, ws, b2, partial);
  reduce_kernel<<<1, 256, 0, stream>>>(partial, out);
}

// Round 9
// 145.766 us; speedup vs baseline: 1.6076x; 1.0068x over previous
//
#include <hip/hip_runtime.h>
#include <hip/hip_bf16.h>

#define BATCH 32
#define CH 3
#define HH 256
#define WW 256
#define KS 29
#define PAD 14
#define NT_F 1000.0f

typedef __attribute__((ext_vector_type(8))) short short8;
typedef __attribute__((ext_vector_type(4))) float f32x4;

union U4 { short8 s8; uint4 u4; };

__device__ inline unsigned short bf16rne(float f) {
  unsigned u = __float_as_uint(f);
  unsigned r = (u + 0x7FFFu + ((u >> 16) & 1u)) >> 16;
  return (unsigned short)r;
}
__device__ inline unsigned pk_bf16(float a, float b) {
  union { __hip_bfloat162 h2; unsigned u; } cv;
  cv.h2 = __float22bfloat162_rn(make_float2(a, b));
  return cv.u;
}

// ws float layout:
//   (unused)  [1024]          @ 0
//   tcond [32][32]            @ 1024
//   w1k   ushort[32][32]      @ 2048  (B-frag conv1 weights, custom k-order)
//   w1g   ushort[32][4]       @ 2560  (conv1 leftover tap (dy2,dx2), ci pad 4)
//   w2c   ushort[9][16][32]   @ 2624  ([tap][n=oc(16)][kn], kn = och-interleave)
//   z     ushort[32][3][256][256] @ 4928  (bf16 blurred)
//   partial float[8192]       @ 3150656
//
// conv1 k-order (k=q*8+j, ci=j&3): q<3: (dy=q,dx=j>>2,ci); q3: (dy=j>>2,dx=2,ci)
//   second MFMA (K=4): j0..3 = (dy=2,dx=2,ci)
// kn interleave: kn even -> och=kn/2, odd -> och=kn/2+16

#define PARTIAL_OFF 3150656

// ---------------- blur (+ embedded weight-prep in block 768) ----------------
__global__ __launch_bounds__(256, 3) void blur_kernel(
    const float* __restrict__ x, const int* __restrict__ t,
    const float* __restrict__ sched, const float* __restrict__ W1,
    const float* __restrict__ b1, const float* __restrict__ tw,
    const float* __restrict__ W2, float* __restrict__ ws,
    unsigned short* __restrict__ z) {
  int blk = blockIdx.x;
  int tid = threadIdx.x;

  if (blk >= BATCH * CH * 8) {
    // ---- weight-prep block (runs once; convloss launches after this kernel)
    float* tcond = ws + 1024;
    unsigned short* w1k = (unsigned short*)(ws + 2048);
    unsigned short* w1g = (unsigned short*)(ws + 2560);
    unsigned short* w2c = (unsigned short*)(ws + 2624);
    for (int i = tid; i < 1024; i += 256) {          // w1k
      int o = i >> 5, k = i & 31;
      int q = k >> 3, j = k & 7, ci = j & 3;
      int dy, dx;
      if (q < 3) { dy = q; dx = j >> 2; } else { dy = j >> 2; dx = 2; }
      w1k[i] = (ci < 3) ? bf16rne(W1[o * 27 + ci * 9 + dy * 3 + dx]) : (unsigned short)0;
    }
    for (int i = tid; i < 128; i += 256) {           // w1g
      int o = i >> 2, j = i & 3;
      w1g[i] = (j < 3) ? bf16rne(W1[o * 27 + j * 9 + 8]) : (unsigned short)0;
    }
    for (int i = tid; i < 4608; i += 256) {          // w2c [tap][oc(16)][kn(32)]
      int tap = i >> 9, r = i & 511;
      int n = r >> 5, kn = r & 31;
      int och = (kn >> 1) + ((kn & 1) ? 16 : 0);
      int dy = tap / 3, dx = tap - dy * 3;
      w2c[i] = (n < 3) ? bf16rne(W2[((n * 32 + och) * 3 + dy) * 3 + dx])
                       : (unsigned short)0;
    }
    for (int i = tid; i < 1024; i += 256) {          // tcond
      int b = i >> 5, o = i & 31;
      tcond[i] = b1[o] + ((float)t[b] * (1.0f / NT_F)) * tw[o];
    }
    return;
  }

  __shared__ float vsp[32][288];   // padded cols: idx = col + 16
  __shared__ float gkl[32];
  int rg = blk & 7;
  int bc = blk >> 3;
  int b = bc / CH;
  int y0 = rg * 32;
  const float* xp = x + (size_t)bc * (HH * WW);

  // issue the 60 column loads first (independent of gk)
  float xv[60];
#pragma unroll
  for (int i = 0; i < 60; i++) {
    int gy = y0 - PAD + i;
    gy = (gy < 0) ? -gy : gy;
    gy = (gy >= HH) ? (2 * HH - 2 - gy) : gy;
    xv[i] = xp[gy * WW + tid];
  }

  // wave 0 computes this batch's gaussian kernel into LDS
  if (tid < 64) {
    float wexp = 0.0f;
    if (tid < KS) {
      float sigma = sched[t[b]];
      float xg = (float)(tid - PAD) / sigma;
      wexp = expf(-0.5f * xg * xg);
    }
    float s = wexp;
#pragma unroll
    for (int off = 32; off > 0; off >>= 1) s += __shfl_down(s, off);
    float tot = __shfl(s, 0);
    if (tid < 32) gkl[tid] = wexp / tot;
  }
  __syncthreads();

  float acc[32];
#pragma unroll
  for (int yy = 0; yy < 32; yy++) acc[yy] = 0.0f;
#pragma unroll
  for (int kk = 0; kk < KS; kk++) {
    float kv = gkl[kk];
#pragma unroll
    for (int yy = 0; yy < 32; yy++) acc[yy] += kv * xv[yy + kk];
  }
#pragma unroll
  for (int yy = 0; yy < 32; yy++) vsp[yy][tid + 16] = acc[yy];
  __syncthreads();
  {
    int row = tid >> 4, i2 = tid & 15;
#pragma unroll
    for (int r2 = 0; r2 < 2; r2++) {
      int rr = row + 16 * r2;
      vsp[rr][i2] = vsp[rr][32 - i2];
      vsp[rr][272 + i2] = vsp[rr][270 - i2];
    }
  }
  __syncthreads();

  size_t zb = (size_t)bc * (HH * WW);
#pragma unroll
  for (int it = 0; it < 8; ++it) {
    int unit = tid + 256 * it;
    int row = unit >> 6, cg = unit & 63;
    float w[36];
#pragma unroll
    for (int i = 0; i < 9; i++)
      *(float4*)&w[4 * i] = *(const float4*)&vsp[row][4 * (cg + i)];
    float o0 = 0, o1 = 0, o2 = 0, o3 = 0;
#pragma unroll
    for (int kk = 0; kk < KS; kk++) {
      float kv = gkl[kk];
      o0 += kv * w[2 + kk];
      o1 += kv * w[3 + kk];
      o2 += kv * w[4 + kk];
      o3 += kv * w[5 + kk];
    }
    unsigned u0 = pk_bf16(o0, o1);
    unsigned u1 = pk_bf16(o2, o3);
    *(uint2*)&z[zb + (size_t)(y0 + row) * WW + 4 * cg] = make_uint2(u0, u1);
  }
}

// ---------------- fused conv1+ReLU+conv2+MSE via bf16 MFMA ----------------
// grid (16,16,B); block 256 = 4 waves; h computed on full 20x20 (garbage edges
// never read by conv2) -> linear p mapping, no div/clamp/guard in hot loops
__global__ __launch_bounds__(256, 4) void convloss_kernel(
    const float* __restrict__ x, const float* __restrict__ ws,
    const float* __restrict__ b2g, float* __restrict__ partial) {
  __shared__ __align__(16) unsigned short zs4[448 * 4];   // [y*20+x][ci0..2,pad]
  __shared__ __align__(16) unsigned short hs[400 * 40];   // [p20][kn(32)+pad8]
  __shared__ float wsum[4];

  const float* tcond = ws + 1024;
  const unsigned short* w1k = (const unsigned short*)(ws + 2048);
  const unsigned short* w1g = (const unsigned short*)(ws + 2560);
  const unsigned short* w2c = (const unsigned short*)(ws + 2624);
  const unsigned short* zg = (const unsigned short*)(ws + 4928);

  int bx = blockIdx.x, by = blockIdx.y, b = blockIdx.z;
  int tid = threadIdx.x;
  int x0 = bx * 16, y0 = by * 16;
  const unsigned short* zbp = zg + (size_t)b * 3 * HH * WW;

  int lane = tid & 63;
  int q = lane >> 4;        // quad 0..3
  int col = lane & 15;      // MFMA m/n index
  int wv = tid >> 6;        // wave id

  // stage z tile (448 slots incl. tap-overrun pad), channel-interleaved
#pragma unroll
  for (int r = 0; r < 2; r++) {
    int unit = tid + 256 * r;
    if (unit < 448) {
      int zy = unit / 20, zx = unit - zy * 20;
      int gy = y0 - 2 + zy, gx = x0 - 2 + zx;
      unsigned c0 = 0, c1 = 0, c2 = 0;
      if ((unsigned)gy < (unsigned)HH && (unsigned)gx < (unsigned)WW) {
        int gi = gy * WW + gx;
        c0 = zbp[gi];
        c1 = zbp[HH * WW + gi];
        c2 = zbp[2 * HH * WW + gi];
      }
      *(uint2*)&zs4[unit * 4] = make_uint2(c0 | (c1 << 16), c2);
    }
  }

  // prefetch MSE x reads
  const float* xb = x + (size_t)b * 3 * HH * WW;
  int colc = (col < 3) ? col : 0;
  float4 xpre[4];
#pragma unroll
  for (int i = 0; i < 4; i++) {
    int g2 = wv * 4 + i;
    xpre[i] = *(const float4*)&xb[colc * (HH * WW) + (y0 + g2) * WW + x0 + q * 4];
  }

  // conv1 B fragments
  U4 B1a, B1b, B2a, B2b;
  B1a.u4 = *(const uint4*)(w1k + col * 32 + q * 8);
  B1b.u4 = *(const uint4*)(w1k + (col + 16) * 32 + q * 8);
  {
    uint2 ta = *(const uint2*)(w1g + col * 4);
    uint2 tb = *(const uint2*)(w1g + (col + 16) * 4);
    bool q0 = (q == 0);
    B2a.u4 = make_uint4(q0 ? ta.x : 0u, q0 ? ta.y : 0u, 0u, 0u);
    B2b.u4 = make_uint4(q0 ? tb.x : 0u, q0 ? tb.y : 0u, 0u, 0u);
  }
  float tc0 = tcond[b * 32 + col];
  float tc1 = tcond[b * 32 + 16 + col];
  float b2v = b2g[colc];
  const f32x4 tcv0 = {tc0, tc0, tc0, tc0};
  const f32x4 tcv1 = {tc1, tc1, tc1, tc1};

  __syncthreads();   // B1: z staged

  // per-lane constant tap offsets (ushort-quad units)
  int dyq = (q < 3) ? q : 0;
  int dxq = (q < 3) ? 0 : 2;
  int strBpx = (q < 3) ? 1 : 20;
  int baseoff = dyq * 20 + dxq;

  // ---- P1: conv1 -> h on 20x20, 32 och; bias via MFMA C-init ----
#pragma unroll
  for (int i = 0; i < 7; i++) {
    int g = wv + 4 * i;
    if (g < 25) {                 // wave-uniform guard
      int p = g * 16 + col;       // linear pixel id on the 20x20 grid
      uint2 lo = *(const uint2*)&zs4[(p + baseoff) * 4];
      uint2 hi = *(const uint2*)&zs4[(p + baseoff + strBpx) * 4];
      U4 A1;
      A1.u4 = make_uint4(lo.x, lo.y, hi.x, hi.y);
      uint2 t2 = *(const uint2*)&zs4[(p + 42) * 4];
      U4 A2;
      bool q0 = (q == 0);
      A2.u4 = make_uint4(q0 ? t2.x : 0u, q0 ? t2.y : 0u, 0u, 0u);
      f32x4 acc0 = __builtin_amdgcn_mfma_f32_16x16x32_bf16(A1.s8, B1a.s8, tcv0, 0, 0, 0);
      acc0 = __builtin_amdgcn_mfma_f32_16x16x32_bf16(A2.s8, B2a.s8, acc0, 0, 0, 0);
      f32x4 acc1 = __builtin_amdgcn_mfma_f32_16x16x32_bf16(A1.s8, B1b.s8, tcv1, 0, 0, 0);
      acc1 = __builtin_amdgcn_mfma_f32_16x16x32_bf16(A2.s8, B2b.s8, acc1, 0, 0, 0);
      int prow = g * 16 + q * 4;
#pragma unroll
      for (int r = 0; r < 4; r++) {
        unsigned pk = pk_bf16(fmaxf(acc0[r], 0.0f), fmaxf(acc1[r], 0.0f));
        *(unsigned*)&hs[(prow + r) * 40 + 2 * col] = pk;
      }
    }
  }
  __syncthreads();   // B2: h complete

  // ---- conv2 as direct implicit GEMM; bias via C-init ----
  const f32x4 bcv = {b2v, b2v, b2v, b2v};
  f32x4 dacc[4];
#pragma unroll
  for (int i = 0; i < 4; i++) dacc[i] = bcv;
#pragma unroll
  for (int tap = 0; tap < 9; tap++) {
    const int dy = tap / 3, dx = tap - (tap / 3) * 3;
    U4 Bt;
    Bt.u4 = *(const uint4*)(w2c + tap * 512 + col * 32 + q * 8);
#pragma unroll
    for (int i = 0; i < 4; i++) {
      int p20 = (wv * 4 + i + dy) * 20 + (col + dx);
      U4 A;
      A.u4 = *(const uint4*)&hs[p20 * 40 + q * 8];   // ds_read_b128, imm offsets
      dacc[i] = __builtin_amdgcn_mfma_f32_16x16x32_bf16(A.s8, Bt.s8, dacc[i], 0, 0, 0);
    }
  }

  // ---- MSE partial (oc=col<3, ox=q*4+r, oy=wv*4+i) ----
  float s = 0.0f;
  if (col < 3) {
#pragma unroll
    for (int i = 0; i < 4; i++) {
      float4 xv = xpre[i];
      float d0 = xv.x - dacc[i][0];
      float d1 = xv.y - dacc[i][1];
      float d2 = xv.z - dacc[i][2];
      float d3 = xv.w - dacc[i][3];
      s += d0 * d0 + d1 * d1 + d2 * d2 + d3 * d3;
    }
  }
#pragma unroll
  for (int off = 32; off > 0; off >>= 1) s += __shfl_down(s, off);
  if (lane == 0) wsum[wv] = s;
  __syncthreads();   // B3
  if (tid == 0) {
    int bid = (b * 16 + by) * 16 + bx;
    partial[bid] = wsum[0] + wsum[1] + wsum[2] + wsum[3];
  }
}

// ---------------- final reduce: 8192 partials -> out[0] ----------------
__global__ __launch_bounds__(256) void reduce_kernel(const float* __restrict__ partial,
                                                     float* __restrict__ out) {
  __shared__ float wsum[4];
  int tid = threadIdx.x;
  float s = 0.0f;
#pragma unroll
  for (int i = 0; i < 8; i++) {
    float4 v = *(const float4*)&partial[(tid + 256 * i) * 4];
    s += v.x + v.y + v.z + v.w;
  }
#pragma unroll
  for (int off = 32; off > 0; off >>= 1) s += __shfl_down(s, off);
  if ((tid & 63) == 0) wsum[tid >> 6] = s;
  __syncthreads();
  if (tid == 0)
    out[0] = (wsum[0] + wsum[1] + wsum[2] + wsum[3]) * (1.0f / 6291456.0f);
}

extern "C" void kernel_launch(void* const* d_in, const int* in_sizes, int n_in,
                              void* d_out, int out_size, void* d_ws, size_t ws_size,
                              hipStream_t stream) {
  const float* x = (const float*)d_in[0];
  const int* t = (const int*)d_in[1];
  const float* W1 = (const float*)d_in[2];
  const float* b1 = (const float*)d_in[3];
  const float* tw = (const float*)d_in[4];
  const float* W2 = (const float*)d_in[5];
  const float* b2 = (const float*)d_in[6];
  const float* sched = (const float*)d_in[7];
  float* out = (float*)d_out;
  float* ws = (float*)d_ws;
  unsigned short* z = (unsigned short*)(ws + 4928);
  float* partial = ws + PARTIAL_OFF;

  blur_kernel<<<BATCH * CH * 8 + 1, 256, 0, stream>>>(x, t, sched, W1, b1, tw, W2, ws, z);
  dim3 grid(16, 16, BATCH);
  convloss_kernel<<<grid, 256, 0, stream>>>(x, ws, b2, partial);
  reduce_kernel<<<1, 256, 0, stream>>>(partial, out);
}

// Round 10
// 141.942 us; speedup vs baseline: 1.6509x; 1.0269x over previous
//
#include <hip/hip_runtime.h>
#include <hip/hip_bf16.h>

#define BATCH 32
#define CH 3
#define HH 256
#define WW 256
#define KS 29
#define PAD 14
#define NT_F 1000.0f

typedef __attribute__((ext_vector_type(8))) short short8;
typedef __attribute__((ext_vector_type(4))) float f32x4;

union U4 { short8 s8; uint4 u4; };

__device__ inline unsigned short bf16rne(float f) {
  unsigned u = __float_as_uint(f);
  unsigned r = (u + 0x7FFFu + ((u >> 16) & 1u)) >> 16;
  return (unsigned short)r;
}
__device__ inline unsigned pk_bf16(float a, float b) {
  union { __hip_bfloat162 h2; unsigned u; } cv;
  cv.h2 = __float22bfloat162_rn(make_float2(a, b));
  return cv.u;
}

// ws float layout:
//   (unused)  [1024]          @ 0
//   tcond [32][32]            @ 1024
//   w1k   ushort[32][32]      @ 2048  (B-frag conv1 weights, custom k-order)
//   w1g   ushort[32][4]       @ 2560  (conv1 leftover tap (dy2,dx2), ci pad 4)
//   w2c   ushort[9][16][32]   @ 2624  ([tap][n=oc(16)][kn], kn = och-interleave)
//   z     ushort[32][3][256][256] @ 4928  (bf16 blurred)
//   partial float[8192]       @ 3150656
//
// conv1 k-order (k=q*8+j, ci=j&3): q<3: (dy=q,dx=j>>2,ci); q3: (dy=j>>2,dx=2,ci)
//   second MFMA (K=4): j0..3 = (dy=2,dx=2,ci)
// kn interleave: kn even -> och=kn/2, odd -> och=kn/2+16

#define PARTIAL_OFF 3150656

// ---------------- blur (+ embedded weight-prep in block 768) ----------------
__global__ __launch_bounds__(256, 3) void blur_kernel(
    const float* __restrict__ x, const int* __restrict__ t,
    const float* __restrict__ sched, const float* __restrict__ W1,
    const float* __restrict__ b1, const float* __restrict__ tw,
    const float* __restrict__ W2, float* __restrict__ ws,
    unsigned short* __restrict__ z) {
  int blk = blockIdx.x;
  int tid = threadIdx.x;

  if (blk >= BATCH * CH * 8) {
    // ---- weight-prep block (runs once; convloss launches after this kernel)
    float* tcond = ws + 1024;
    unsigned short* w1k = (unsigned short*)(ws + 2048);
    unsigned short* w1g = (unsigned short*)(ws + 2560);
    unsigned short* w2c = (unsigned short*)(ws + 2624);
    for (int i = tid; i < 1024; i += 256) {          // w1k
      int o = i >> 5, k = i & 31;
      int q = k >> 3, j = k & 7, ci = j & 3;
      int dy, dx;
      if (q < 3) { dy = q; dx = j >> 2; } else { dy = j >> 2; dx = 2; }
      w1k[i] = (ci < 3) ? bf16rne(W1[o * 27 + ci * 9 + dy * 3 + dx]) : (unsigned short)0;
    }
    for (int i = tid; i < 128; i += 256) {           // w1g
      int o = i >> 2, j = i & 3;
      w1g[i] = (j < 3) ? bf16rne(W1[o * 27 + j * 9 + 8]) : (unsigned short)0;
    }
    for (int i = tid; i < 4608; i += 256) {          // w2c [tap][oc(16)][kn(32)]
      int tap = i >> 9, r = i & 511;
      int n = r >> 5, kn = r & 31;
      int och = (kn >> 1) + ((kn & 1) ? 16 : 0);
      int dy = tap / 3, dx = tap - dy * 3;
      w2c[i] = (n < 3) ? bf16rne(W2[((n * 32 + och) * 3 + dy) * 3 + dx])
                       : (unsigned short)0;
    }
    for (int i = tid; i < 1024; i += 256) {          // tcond
      int b = i >> 5, o = i & 31;
      tcond[i] = b1[o] + ((float)t[b] * (1.0f / NT_F)) * tw[o];
    }
    return;
  }

  __shared__ float vsp[32][288];   // padded cols: idx = col + 16
  __shared__ float gkl[32];
  int rg = blk & 7;
  int bc = blk >> 3;
  int b = bc / CH;
  int y0 = rg * 32;
  const float* xp = x + (size_t)bc * (HH * WW);

  // issue the 60 column loads first (independent of gk)
  float xv[60];
#pragma unroll
  for (int i = 0; i < 60; i++) {
    int gy = y0 - PAD + i;
    gy = (gy < 0) ? -gy : gy;
    gy = (gy >= HH) ? (2 * HH - 2 - gy) : gy;
    xv[i] = xp[gy * WW + tid];
  }

  // wave 0 computes this batch's gaussian kernel into LDS
  if (tid < 64) {
    float wexp = 0.0f;
    if (tid < KS) {
      float sigma = sched[t[b]];
      float xg = (float)(tid - PAD) / sigma;
      wexp = expf(-0.5f * xg * xg);
    }
    float s = wexp;
#pragma unroll
    for (int off = 32; off > 0; off >>= 1) s += __shfl_down(s, off);
    float tot = __shfl(s, 0);
    if (tid < 32) gkl[tid] = wexp / tot;
  }
  __syncthreads();

  float acc[32];
#pragma unroll
  for (int yy = 0; yy < 32; yy++) acc[yy] = 0.0f;
#pragma unroll
  for (int kk = 0; kk < KS; kk++) {
    float kv = gkl[kk];
#pragma unroll
    for (int yy = 0; yy < 32; yy++) acc[yy] += kv * xv[yy + kk];
  }
#pragma unroll
  for (int yy = 0; yy < 32; yy++) vsp[yy][tid + 16] = acc[yy];
  __syncthreads();
  {
    int row = tid >> 4, i2 = tid & 15;
#pragma unroll
    for (int r2 = 0; r2 < 2; r2++) {
      int rr = row + 16 * r2;
      vsp[rr][i2] = vsp[rr][32 - i2];
      vsp[rr][272 + i2] = vsp[rr][270 - i2];
    }
  }
  __syncthreads();

  size_t zb = (size_t)bc * (HH * WW);
#pragma unroll
  for (int it = 0; it < 8; ++it) {
    int unit = tid + 256 * it;
    int row = unit >> 6, cg = unit & 63;
    float w[36];
#pragma unroll
    for (int i = 0; i < 9; i++)
      *(float4*)&w[4 * i] = *(const float4*)&vsp[row][4 * (cg + i)];
    float o0 = 0, o1 = 0, o2 = 0, o3 = 0;
#pragma unroll
    for (int kk = 0; kk < KS; kk++) {
      float kv = gkl[kk];
      o0 += kv * w[2 + kk];
      o1 += kv * w[3 + kk];
      o2 += kv * w[4 + kk];
      o3 += kv * w[5 + kk];
    }
    unsigned u0 = pk_bf16(o0, o1);
    unsigned u1 = pk_bf16(o2, o3);
    *(uint2*)&z[zb + (size_t)(y0 + row) * WW + 4 * cg] = make_uint2(u0, u1);
  }
}

// ---------------- fused conv1+ReLU+conv2+MSE via bf16 MFMA ----------------
// grid (16,16,B); block 256 = 4 waves; 16x16 output tile
// h on 18x18; conv1 groups row-structured (18 row-groups + 3 halo groups)
// -> no division / clamp / store-guard in the hot loops.
__global__ __launch_bounds__(256, 5) void convloss_kernel(
    const float* __restrict__ x, const float* __restrict__ ws,
    const float* __restrict__ b2g, float* __restrict__ partial) {
  __shared__ __align__(16) unsigned short zs4[400 * 4];   // [y*20+x][ci0..2,pad]
  __shared__ __align__(16) unsigned short hs[324 * 40];   // [hy*18+hx][kn(32)+pad8]
  __shared__ float wsum[4];

  const float* tcond = ws + 1024;
  const unsigned short* w1k = (const unsigned short*)(ws + 2048);
  const unsigned short* w1g = (const unsigned short*)(ws + 2560);
  const unsigned short* w2c = (const unsigned short*)(ws + 2624);
  const unsigned short* zg = (const unsigned short*)(ws + 4928);

  int bx = blockIdx.x, by = blockIdx.y, b = blockIdx.z;
  int tid = threadIdx.x;
  int x0 = bx * 16, y0 = by * 16;
  const unsigned short* zbp = zg + (size_t)b * 3 * HH * WW;

  int lane = tid & 63;
  int q = lane >> 4;        // quad 0..3
  int col = lane & 15;      // MFMA m/n index
  int wv = tid >> 6;        // wave id

  // stage z tile (20x20), channel-interleaved, zero outside image
#pragma unroll
  for (int r = 0; r < 2; r++) {
    int unit = tid + 256 * r;
    if (unit < 400) {
      int zy = unit / 20, zx = unit - zy * 20;
      int gy = y0 - 2 + zy, gx = x0 - 2 + zx;
      unsigned c0 = 0, c1 = 0, c2 = 0;
      if ((unsigned)gy < (unsigned)HH && (unsigned)gx < (unsigned)WW) {
        int gi = gy * WW + gx;
        c0 = zbp[gi];
        c1 = zbp[HH * WW + gi];
        c2 = zbp[2 * HH * WW + gi];
      }
      *(uint2*)&zs4[unit * 4] = make_uint2(c0 | (c1 << 16), c2);
    }
  }

  // prefetch MSE x reads
  const float* xb = x + (size_t)b * 3 * HH * WW;
  int colc = (col < 3) ? col : 0;
  float4 xpre[4];
#pragma unroll
  for (int i = 0; i < 4; i++) {
    int g2 = wv * 4 + i;
    xpre[i] = *(const float4*)&xb[colc * (HH * WW) + (y0 + g2) * WW + x0 + q * 4];
  }

  // conv1 B fragments
  U4 B1a, B1b, B2a, B2b;
  B1a.u4 = *(const uint4*)(w1k + col * 32 + q * 8);
  B1b.u4 = *(const uint4*)(w1k + (col + 16) * 32 + q * 8);
  {
    uint2 ta = *(const uint2*)(w1g + col * 4);
    uint2 tb = *(const uint2*)(w1g + (col + 16) * 4);
    bool q0 = (q == 0);
    B2a.u4 = make_uint4(q0 ? ta.x : 0u, q0 ? ta.y : 0u, 0u, 0u);
    B2b.u4 = make_uint4(q0 ? tb.x : 0u, q0 ? tb.y : 0u, 0u, 0u);
  }
  float tc0 = tcond[b * 32 + col];
  float tc1 = tcond[b * 32 + 16 + col];
  float b2v = b2g[colc];
  const f32x4 tcv0 = {tc0, tc0, tc0, tc0};
  const f32x4 tcv1 = {tc1, tc1, tc1, tc1};

  __syncthreads();   // B1: z staged

  // per-lane constant tap offsets (px units on the 20-wide z tile)
  int dyq = (q < 3) ? q : 0;
  int dxq = (q < 3) ? 0 : 2;
  int strBpx = (q < 3) ? 1 : 20;

  // ---- P1: conv1 -> h (18x18, 32 och) ----
  // groups g: 0..17 = h rows (py=g, px=col);  18..20 = halo cols 16..17
#pragma unroll
  for (int i = 0; i < 6; i++) {
    int g = wv + 4 * i;
    if (g < 21) {                 // wave-uniform guard
      int py_a, px_a;
      if (g < 18) {               // wave-uniform branch
        py_a = g; px_a = col;
      } else {
        int u = (g - 18) * 16 + col;
        u = (u > 35) ? 35 : u;    // duplicate lanes recompute px (17,17): benign
        py_a = u >> 1; px_a = 16 + (u & 1);
      }
      int lo_i = (py_a + dyq) * 20 + px_a + dxq;
      uint2 lo = *(const uint2*)&zs4[lo_i * 4];
      uint2 hi = *(const uint2*)&zs4[(lo_i + strBpx) * 4];
      U4 A1;
      A1.u4 = make_uint4(lo.x, lo.y, hi.x, hi.y);
      uint2 t2 = *(const uint2*)&zs4[((py_a + 2) * 20 + px_a + 2) * 4];
      U4 A2;
      bool q0 = (q == 0);
      A2.u4 = make_uint4(q0 ? t2.x : 0u, q0 ? t2.y : 0u, 0u, 0u);
      f32x4 acc0 = __builtin_amdgcn_mfma_f32_16x16x32_bf16(A1.s8, B1a.s8, tcv0, 0, 0, 0);
      acc0 = __builtin_amdgcn_mfma_f32_16x16x32_bf16(A2.s8, B2a.s8, acc0, 0, 0, 0);
      f32x4 acc1 = __builtin_amdgcn_mfma_f32_16x16x32_bf16(A1.s8, B1b.s8, tcv1, 0, 0, 0);
      acc1 = __builtin_amdgcn_mfma_f32_16x16x32_bf16(A2.s8, B2b.s8, acc1, 0, 0, 0);
      if (g < 18) {
        int pb = (g * 18 + q * 4) * 40 + 2 * col;
#pragma unroll
        for (int r = 0; r < 4; r++) {
          unsigned pk = pk_bf16(fmaxf(acc0[r], 0.0f), fmaxf(acc1[r], 0.0f));
          *(unsigned*)&hs[pb + r * 40] = pk;
        }
      } else {
        int ub = (g - 18) * 16 + q * 4;
#pragma unroll
        for (int r = 0; r < 4; r++) {
          int u2 = ub + r;
          u2 = (u2 > 35) ? 35 : u2;   // duplicate writes carry identical values
          unsigned pk = pk_bf16(fmaxf(acc0[r], 0.0f), fmaxf(acc1[r], 0.0f));
          *(unsigned*)&hs[((u2 >> 1) * 18 + 16 + (u2 & 1)) * 40 + 2 * col] = pk;
        }
      }
    }
  }
  __syncthreads();   // B2: h complete

  // ---- conv2 as direct implicit GEMM; bias via C-init ----
  const f32x4 bcv = {b2v, b2v, b2v, b2v};
  f32x4 dacc[4];
#pragma unroll
  for (int i = 0; i < 4; i++) dacc[i] = bcv;
#pragma unroll
  for (int tap = 0; tap < 9; tap++) {
    const int dy = tap / 3, dx = tap - (tap / 3) * 3;
    U4 Bt;
    Bt.u4 = *(const uint4*)(w2c + tap * 512 + col * 32 + q * 8);
#pragma unroll
    for (int i = 0; i < 4; i++) {
      int p18 = (wv * 4 + i + dy) * 18 + (col + dx);
      U4 A;
      A.u4 = *(const uint4*)&hs[p18 * 40 + q * 8];   // ds_read_b128
      dacc[i] = __builtin_amdgcn_mfma_f32_16x16x32_bf16(A.s8, Bt.s8, dacc[i], 0, 0, 0);
    }
  }

  // ---- MSE partial (oc=col<3, ox=q*4+r, oy=wv*4+i) ----
  float s = 0.0f;
  if (col < 3) {
#pragma unroll
    for (int i = 0; i < 4; i++) {
      float4 xv = xpre[i];
      float d0 = xv.x - dacc[i][0];
      float d1 = xv.y - dacc[i][1];
      float d2 = xv.z - dacc[i][2];
      float d3 = xv.w - dacc[i][3];
      s += d0 * d0 + d1 * d1 + d2 * d2 + d3 * d3;
    }
  }
#pragma unroll
  for (int off = 32; off > 0; off >>= 1) s += __shfl_down(s, off);
  if (lane == 0) wsum[wv] = s;
  __syncthreads();   // B3
  if (tid == 0) {
    int bid = (b * 16 + by) * 16 + bx;
    partial[bid] = wsum[0] + wsum[1] + wsum[2] + wsum[3];
  }
}

// ---------------- final reduce: 8192 partials -> out[0] ----------------
__global__ __launch_bounds__(256) void reduce_kernel(const float* __restrict__ partial,
                                                     float* __restrict__ out) {
  __shared__ float wsum[4];
  int tid = threadIdx.x;
  float s = 0.0f;
#pragma unroll
  for (int i = 0; i < 8; i++) {
    float4 v = *(const float4*)&partial[(tid + 256 * i) * 4];
    s += v.x + v.y + v.z + v.w;
  }
#pragma unroll
  for (int off = 32; off > 0; off >>= 1) s += __shfl_down(s, off);
  if ((tid & 63) == 0) wsum[tid >> 6] = s;
  __syncthreads();
  if (tid == 0)
    out[0] = (wsum[0] + wsum[1] + wsum[2] + wsum[3]) * (1.0f / 6291456.0f);
}

extern "C" void kernel_launch(void* const* d_in, const int* in_sizes, int n_in,
                              void* d_out, int out_size, void* d_ws, size_t ws_size,
                              hipStream_t stream) {
  const float* x = (const float*)d_in[0];
  const int* t = (const int*)d_in[1];
  const float* W1 = (const float*)d_in[2];
  const float* b1 = (const float*)d_in[3];
  const float* tw = (const float*)d_in[4];
  const float* W2 = (const float*)d_in[5];
  const float* b2 = (const float*)d_in[6];
  const float* sched = (const float*)d_in[7];
  float* out = (float*)d_out;
  float* ws = (float*)d_ws;
  unsigned short* z = (unsigned short*)(ws + 4928);
  float* partial = ws + PARTIAL_OFF;

  blur_kernel<<<BATCH * CH * 8 + 1, 256, 0, stream>>>(x, t, sched, W1, b1, tw, W2, ws, z);
  dim3 grid(16, 16, BATCH);
  convloss_kernel<<<grid, 256, 0, stream>>>(x, ws, b2, partial);
  reduce_kernel<<<1, 256, 0, stream>>>(partial, out);
}

// Round 11
// 141.527 us; speedup vs baseline: 1.6557x; 1.0029x over previous
//
#include <hip/hip_runtime.h>
#include <hip/hip_bf16.h>

#define BATCH 32
#define CH 3
#define HH 256
#define WW 256
#define KS 29
#define PAD 14
#define NT_F 1000.0f

typedef __attribute__((ext_vector_type(8))) short short8;
typedef __attribute__((ext_vector_type(4))) float f32x4;

union U4 { short8 s8; uint4 u4; };

__device__ inline unsigned short bf16rne(float f) {
  unsigned u = __float_as_uint(f);
  unsigned r = (u + 0x7FFFu + ((u >> 16) & 1u)) >> 16;
  return (unsigned short)r;
}
__device__ inline unsigned pk_bf16(float a, float b) {
  union { __hip_bfloat162 h2; unsigned u; } cv;
  cv.h2 = __float22bfloat162_rn(make_float2(a, b));
  return cv.u;
}

// ws float layout:
//   (unused)  [1024]          @ 0
//   tcond [32][32]            @ 1024
//   w1k   ushort[32][32]      @ 2048  (B-frag conv1 weights, custom k-order)
//   w1g   ushort[32][4]       @ 2560  (conv1 leftover tap (dy2,dx2), ci pad 4)
//   w2c   ushort[9][16][32]   @ 2624  ([tap][n=oc(16)][kn], kn = och-interleave)
//   z     ushort[32][3][256][256] @ 4928  (bf16 blurred)
//   partial float[8192]       @ 3150656
//
// conv1 k-order (k=q*8+j, ci=j&3): q<3: (dy=q,dx=j>>2,ci); q3: (dy=j>>2,dx=2,ci)
//   second MFMA (K=4): j0..3 = (dy=2,dx=2,ci)
// kn interleave: kn even -> och=kn/2, odd -> och=kn/2+16

#define PARTIAL_OFF 3150656

// ---------------- blur (+ embedded weight-prep in block 768) ----------------
__global__ __launch_bounds__(256, 3) void blur_kernel(
    const float* __restrict__ x, const int* __restrict__ t,
    const float* __restrict__ sched, const float* __restrict__ W1,
    const float* __restrict__ b1, const float* __restrict__ tw,
    const float* __restrict__ W2, float* __restrict__ ws,
    unsigned short* __restrict__ z) {
  int blk = blockIdx.x;
  int tid = threadIdx.x;

  if (blk >= BATCH * CH * 8) {
    // ---- weight-prep block (runs once; convloss launches after this kernel)
    float* tcond = ws + 1024;
    unsigned short* w1k = (unsigned short*)(ws + 2048);
    unsigned short* w1g = (unsigned short*)(ws + 2560);
    unsigned short* w2c = (unsigned short*)(ws + 2624);
    for (int i = tid; i < 1024; i += 256) {          // w1k
      int o = i >> 5, k = i & 31;
      int q = k >> 3, j = k & 7, ci = j & 3;
      int dy, dx;
      if (q < 3) { dy = q; dx = j >> 2; } else { dy = j >> 2; dx = 2; }
      w1k[i] = (ci < 3) ? bf16rne(W1[o * 27 + ci * 9 + dy * 3 + dx]) : (unsigned short)0;
    }
    for (int i = tid; i < 128; i += 256) {           // w1g
      int o = i >> 2, j = i & 3;
      w1g[i] = (j < 3) ? bf16rne(W1[o * 27 + j * 9 + 8]) : (unsigned short)0;
    }
    for (int i = tid; i < 4608; i += 256) {          // w2c [tap][oc(16)][kn(32)]
      int tap = i >> 9, r = i & 511;
      int n = r >> 5, kn = r & 31;
      int och = (kn >> 1) + ((kn & 1) ? 16 : 0);
      int dy = tap / 3, dx = tap - dy * 3;
      w2c[i] = (n < 3) ? bf16rne(W2[((n * 32 + och) * 3 + dy) * 3 + dx])
                       : (unsigned short)0;
    }
    for (int i = tid; i < 1024; i += 256) {          // tcond
      int b = i >> 5, o = i & 31;
      tcond[i] = b1[o] + ((float)t[b] * (1.0f / NT_F)) * tw[o];
    }
    return;
  }

  __shared__ float vsp[32][288];   // padded cols: idx = col + 16
  __shared__ float gkl[32];
  int rg = blk & 7;
  int bc = blk >> 3;
  int b = bc / CH;
  int y0 = rg * 32;
  const float* xp = x + (size_t)bc * (HH * WW);

  // issue the 60 column loads first (independent of gk)
  float xv[60];
#pragma unroll
  for (int i = 0; i < 60; i++) {
    int gy = y0 - PAD + i;
    gy = (gy < 0) ? -gy : gy;
    gy = (gy >= HH) ? (2 * HH - 2 - gy) : gy;
    xv[i] = xp[gy * WW + tid];
  }

  // wave 0 computes this batch's gaussian kernel into LDS
  if (tid < 64) {
    float wexp = 0.0f;
    if (tid < KS) {
      float sigma = sched[t[b]];
      float xg = (float)(tid - PAD) / sigma;
      wexp = expf(-0.5f * xg * xg);
    }
    float s = wexp;
#pragma unroll
    for (int off = 32; off > 0; off >>= 1) s += __shfl_down(s, off);
    float tot = __shfl(s, 0);
    if (tid < 32) gkl[tid] = wexp / tot;
  }
  __syncthreads();

  float acc[32];
#pragma unroll
  for (int yy = 0; yy < 32; yy++) acc[yy] = 0.0f;
#pragma unroll
  for (int kk = 0; kk < KS; kk++) {
    float kv = gkl[kk];
#pragma unroll
    for (int yy = 0; yy < 32; yy++) acc[yy] += kv * xv[yy + kk];
  }
#pragma unroll
  for (int yy = 0; yy < 32; yy++) vsp[yy][tid + 16] = acc[yy];
  __syncthreads();
  {
    int row = tid >> 4, i2 = tid & 15;
#pragma unroll
    for (int r2 = 0; r2 < 2; r2++) {
      int rr = row + 16 * r2;
      vsp[rr][i2] = vsp[rr][32 - i2];
      vsp[rr][272 + i2] = vsp[rr][270 - i2];
    }
  }
  __syncthreads();

  size_t zb = (size_t)bc * (HH * WW);
#pragma unroll
  for (int it = 0; it < 8; ++it) {
    int unit = tid + 256 * it;
    int row = unit >> 6, cg = unit & 63;
    float w[36];
#pragma unroll
    for (int i = 0; i < 9; i++)
      *(float4*)&w[4 * i] = *(const float4*)&vsp[row][4 * (cg + i)];
    float o0 = 0, o1 = 0, o2 = 0, o3 = 0;
#pragma unroll
    for (int kk = 0; kk < KS; kk++) {
      float kv = gkl[kk];
      o0 += kv * w[2 + kk];
      o1 += kv * w[3 + kk];
      o2 += kv * w[4 + kk];
      o3 += kv * w[5 + kk];
    }
    unsigned u0 = pk_bf16(o0, o1);
    unsigned u1 = pk_bf16(o2, o3);
    *(uint2*)&z[zb + (size_t)(y0 + row) * WW + 4 * cg] = make_uint2(u0, u1);
  }
}

// ---------------- fused conv1+ReLU+conv2+MSE via bf16 MFMA ----------------
// grid (16,16,B); block 256 = 4 waves; 16x16 output tile
// conv2 loop-rotated: each h A-frag read ONCE (18 reads), feeding up to 3
// accumulating MFMAs (dy resolved by target accumulator index).
__global__ __launch_bounds__(256, 5) void convloss_kernel(
    const float* __restrict__ x, const float* __restrict__ ws,
    const float* __restrict__ b2g, float* __restrict__ partial) {
  __shared__ __align__(16) unsigned short zs4[400 * 4];   // [y*20+x][ci0..2,pad]
  __shared__ __align__(16) unsigned short hs[324 * 40];   // [hy*18+hx][kn(32)+pad8]
  __shared__ float wsum[4];

  const float* tcond = ws + 1024;
  const unsigned short* w1k = (const unsigned short*)(ws + 2048);
  const unsigned short* w1g = (const unsigned short*)(ws + 2560);
  const unsigned short* w2c = (const unsigned short*)(ws + 2624);
  const unsigned short* zg = (const unsigned short*)(ws + 4928);

  int bx = blockIdx.x, by = blockIdx.y, b = blockIdx.z;
  int tid = threadIdx.x;
  int x0 = bx * 16, y0 = by * 16;
  const unsigned short* zbp = zg + (size_t)b * 3 * HH * WW;

  int lane = tid & 63;
  int q = lane >> 4;        // quad 0..3
  int col = lane & 15;      // MFMA m/n index
  int wv = tid >> 6;        // wave id

  // stage z tile (20x20), channel-interleaved, zero outside image
#pragma unroll
  for (int r = 0; r < 2; r++) {
    int unit = tid + 256 * r;
    if (unit < 400) {
      int zy = unit / 20, zx = unit - zy * 20;
      int gy = y0 - 2 + zy, gx = x0 - 2 + zx;
      unsigned c0 = 0, c1 = 0, c2 = 0;
      if ((unsigned)gy < (unsigned)HH && (unsigned)gx < (unsigned)WW) {
        int gi = gy * WW + gx;
        c0 = zbp[gi];
        c1 = zbp[HH * WW + gi];
        c2 = zbp[2 * HH * WW + gi];
      }
      *(uint2*)&zs4[unit * 4] = make_uint2(c0 | (c1 << 16), c2);
    }
  }

  // prefetch MSE x reads
  const float* xb = x + (size_t)b * 3 * HH * WW;
  int colc = (col < 3) ? col : 0;
  float4 xpre[4];
#pragma unroll
  for (int i = 0; i < 4; i++) {
    int g2 = wv * 4 + i;
    xpre[i] = *(const float4*)&xb[colc * (HH * WW) + (y0 + g2) * WW + x0 + q * 4];
  }

  // conv1 B fragments
  U4 B1a, B1b, B2a, B2b;
  B1a.u4 = *(const uint4*)(w1k + col * 32 + q * 8);
  B1b.u4 = *(const uint4*)(w1k + (col + 16) * 32 + q * 8);
  {
    uint2 ta = *(const uint2*)(w1g + col * 4);
    uint2 tb = *(const uint2*)(w1g + (col + 16) * 4);
    bool q0 = (q == 0);
    B2a.u4 = make_uint4(q0 ? ta.x : 0u, q0 ? ta.y : 0u, 0u, 0u);
    B2b.u4 = make_uint4(q0 ? tb.x : 0u, q0 ? tb.y : 0u, 0u, 0u);
  }
  float tc0 = tcond[b * 32 + col];
  float tc1 = tcond[b * 32 + 16 + col];
  float b2v = b2g[colc];
  const f32x4 tcv0 = {tc0, tc0, tc0, tc0};
  const f32x4 tcv1 = {tc1, tc1, tc1, tc1};

  __syncthreads();   // B1: z staged

  // per-lane constant tap offsets (px units on the 20-wide z tile)
  int dyq = (q < 3) ? q : 0;
  int dxq = (q < 3) ? 0 : 2;
  int strBpx = (q < 3) ? 1 : 20;

  // ---- P1: conv1 -> h (18x18, 32 och) ----
  // groups g: 0..17 = h rows (py=g, px=col);  18..20 = halo cols 16..17
#pragma unroll
  for (int i = 0; i < 6; i++) {
    int g = wv + 4 * i;
    if (g < 21) {                 // wave-uniform guard
      int py_a, px_a;
      if (g < 18) {               // wave-uniform branch
        py_a = g; px_a = col;
      } else {
        int u = (g - 18) * 16 + col;
        u = (u > 35) ? 35 : u;    // duplicate lanes recompute px (17,17): benign
        py_a = u >> 1; px_a = 16 + (u & 1);
      }
      int lo_i = (py_a + dyq) * 20 + px_a + dxq;
      uint2 lo = *(const uint2*)&zs4[lo_i * 4];
      uint2 hi = *(const uint2*)&zs4[(lo_i + strBpx) * 4];
      U4 A1;
      A1.u4 = make_uint4(lo.x, lo.y, hi.x, hi.y);
      uint2 t2 = *(const uint2*)&zs4[((py_a + 2) * 20 + px_a + 2) * 4];
      U4 A2;
      bool q0 = (q == 0);
      A2.u4 = make_uint4(q0 ? t2.x : 0u, q0 ? t2.y : 0u, 0u, 0u);
      f32x4 acc0 = __builtin_amdgcn_mfma_f32_16x16x32_bf16(A1.s8, B1a.s8, tcv0, 0, 0, 0);
      acc0 = __builtin_amdgcn_mfma_f32_16x16x32_bf16(A2.s8, B2a.s8, acc0, 0, 0, 0);
      f32x4 acc1 = __builtin_amdgcn_mfma_f32_16x16x32_bf16(A1.s8, B1b.s8, tcv1, 0, 0, 0);
      acc1 = __builtin_amdgcn_mfma_f32_16x16x32_bf16(A2.s8, B2b.s8, acc1, 0, 0, 0);
      if (g < 18) {
        int pb = (g * 18 + q * 4) * 40 + 2 * col;
#pragma unroll
        for (int r = 0; r < 4; r++) {
          unsigned pk = pk_bf16(fmaxf(acc0[r], 0.0f), fmaxf(acc1[r], 0.0f));
          *(unsigned*)&hs[pb + r * 40] = pk;
        }
      } else {
        int ub = (g - 18) * 16 + q * 4;
#pragma unroll
        for (int r = 0; r < 4; r++) {
          int u2 = ub + r;
          u2 = (u2 > 35) ? 35 : u2;   // duplicate writes carry identical values
          unsigned pk = pk_bf16(fmaxf(acc0[r], 0.0f), fmaxf(acc1[r], 0.0f));
          *(unsigned*)&hs[((u2 >> 1) * 18 + 16 + (u2 & 1)) * 40 + 2 * col] = pk;
        }
      }
    }
  }
  __syncthreads();   // B2: h complete

  // ---- conv2, loop-rotated: 18 A-reads, 36 accumulating MFMAs ----
  const f32x4 bcv = {b2v, b2v, b2v, b2v};
  f32x4 dacc[4];
#pragma unroll
  for (int i = 0; i < 4; i++) dacc[i] = bcv;
  {
    // base LDS address for this wave's h rows (rr=0 => row wv*4, col+0)
    const unsigned short* hbase = &hs[((wv * 4) * 18 + col) * 40 + q * 8];
#pragma unroll
    for (int dx = 0; dx < 3; dx++) {
      U4 Bt0, Bt1, Bt2;
      Bt0.u4 = *(const uint4*)(w2c + (0 * 3 + dx) * 512 + col * 32 + q * 8);
      Bt1.u4 = *(const uint4*)(w2c + (1 * 3 + dx) * 512 + col * 32 + q * 8);
      Bt2.u4 = *(const uint4*)(w2c + (2 * 3 + dx) * 512 + col * 32 + q * 8);
#pragma unroll
      for (int rr = 0; rr < 6; rr++) {
        U4 A;
        A.u4 = *(const uint4*)&hbase[(rr * 18 + dx) * 40];   // one b128, imm offset
        if (rr < 4)
          dacc[rr] = __builtin_amdgcn_mfma_f32_16x16x32_bf16(A.s8, Bt0.s8, dacc[rr], 0, 0, 0);
        if (rr >= 1 && rr < 5)
          dacc[rr - 1] = __builtin_amdgcn_mfma_f32_16x16x32_bf16(A.s8, Bt1.s8, dacc[rr - 1], 0, 0, 0);
        if (rr >= 2)
          dacc[rr - 2] = __builtin_amdgcn_mfma_f32_16x16x32_bf16(A.s8, Bt2.s8, dacc[rr - 2], 0, 0, 0);
      }
    }
  }

  // ---- MSE partial (oc=col<3, ox=q*4+r, oy=wv*4+i) ----
  float s = 0.0f;
  if (col < 3) {
#pragma unroll
    for (int i = 0; i < 4; i++) {
      float4 xv = xpre[i];
      float d0 = xv.x - dacc[i][0];
      float d1 = xv.y - dacc[i][1];
      float d2 = xv.z - dacc[i][2];
      float d3 = xv.w - dacc[i][3];
      s += d0 * d0 + d1 * d1 + d2 * d2 + d3 * d3;
    }
  }
#pragma unroll
  for (int off = 32; off > 0; off >>= 1) s += __shfl_down(s, off);
  if (lane == 0) wsum[wv] = s;
  __syncthreads();   // B3
  if (tid == 0) {
    int bid = (b * 16 + by) * 16 + bx;
    partial[bid] = wsum[0] + wsum[1] + wsum[2] + wsum[3];
  }
}

// ---------------- final reduce: 8192 partials -> out[0] ----------------
__global__ __launch_bounds__(256) void reduce_kernel(const float* __restrict__ partial,
                                                     float* __restrict__ out) {
  __shared__ float wsum[4];
  int tid = threadIdx.x;
  float s = 0.0f;
#pragma unroll
  for (int i = 0; i < 8; i++) {
    float4 v = *(const float4*)&partial[(tid + 256 * i) * 4];
    s += v.x + v.y + v.z + v.w;
  }
#pragma unroll
  for (int off = 32; off > 0; off >>= 1) s += __shfl_down(s, off);
  if ((tid & 63) == 0) wsum[tid >> 6] = s;
  __syncthreads();
  if (tid == 0)
    out[0] = (wsum[0] + wsum[1] + wsum[2] + wsum[3]) * (1.0f / 6291456.0f);
}

extern "C" void kernel_launch(void* const* d_in, const int* in_sizes, int n_in,
                              void* d_out, int out_size, void* d_ws, size_t ws_size,
                              hipStream_t stream) {
  const float* x = (const float*)d_in[0];
  const int* t = (const int*)d_in[1];
  const float* W1 = (const float*)d_in[2];
  const float* b1 = (const float*)d_in[3];
  const float* tw = (const float*)d_in[4];
  const float* W2 = (const float*)d_in[5];
  const float* b2 = (const float*)d_in[6];
  const float* sched = (const float*)d_in[7];
  float* out = (float*)d_out;
  float* ws = (float*)d_ws;
  unsigned short* z = (unsigned short*)(ws + 4928);
  float* partial = ws + PARTIAL_OFF;

  blur_kernel<<<BATCH * CH * 8 + 1, 256, 0, stream>>>(x, t, sched, W1, b1, tw, W2, ws, z);
  dim3 grid(16, 16, BATCH);
  convloss_kernel<<<grid, 256, 0, stream>>>(x, ws, b2, partial);
  reduce_kernel<<<1, 256, 0, stream>>>(partial, out);
}

// Round 12
// 140.557 us; speedup vs baseline: 1.6671x; 1.0069x over previous
//
#include <hip/hip_runtime.h>
#include <hip/hip_bf16.h>

#define BATCH 32
#define CH 3
#define HH 256
#define WW 256
#define KS 29
#define PAD 14
#define NT_F 1000.0f

typedef __attribute__((ext_vector_type(8))) short short8;
typedef __attribute__((ext_vector_type(4))) float f32x4;
typedef __attribute__((ext_vector_type(16))) float f32x16;

union U4 { short8 s8; uint4 u4; };

__device__ inline unsigned short bf16rne(float f) {
  unsigned u = __float_as_uint(f);
  unsigned r = (u + 0x7FFFu + ((u >> 16) & 1u)) >> 16;
  return (unsigned short)r;
}
__device__ inline unsigned pk_bf16(float a, float b) {
  union { __hip_bfloat162 h2; unsigned u; } cv;
  cv.h2 = __float22bfloat162_rn(make_float2(a, b));
  return cv.u;
}

// ws float layout:
//   (unused)  [1024]          @ 0
//   tcond [32][32]            @ 1024
//   w1n   ushort[3][32][16]   @ 2048  ([mf][och][slot]; slot s: tap=mf*4+(s>>2), ci=s&3)
//   w2c   ushort[9][16][32]   @ 2816  ([tap][oc(16)][och] plain order)
//   z     ushort[32][3][256][256] @ 5120  (bf16 blurred)
//   partial float[8192]       @ 3151872
//
// conv1 (32x32x16 MFMA): A=weights[m=och][k=slot], B=z[k=slot][n=pixel],
//   D[n=pixel=lane&31][m=och=(reg&3)+8*(reg>>2)+4*(lane>>5)]
// conv2 (16x16x32 MFMA): unchanged; hs & w2c in plain och order.

#define PARTIAL_OFF 3151872

// ---------------- blur (+ embedded weight-prep in block 768) ----------------
__global__ __launch_bounds__(256, 3) void blur_kernel(
    const float* __restrict__ x, const int* __restrict__ t,
    const float* __restrict__ sched, const float* __restrict__ W1,
    const float* __restrict__ b1, const float* __restrict__ tw,
    const float* __restrict__ W2, float* __restrict__ ws,
    unsigned short* __restrict__ z) {
  int blk = blockIdx.x;
  int tid = threadIdx.x;

  if (blk >= BATCH * CH * 8) {
    // ---- weight-prep block (runs once; convloss launches after this kernel)
    float* tcond = ws + 1024;
    unsigned short* w1n = (unsigned short*)(ws + 2048);
    unsigned short* w2c = (unsigned short*)(ws + 2816);
    for (int i = tid; i < 1536; i += 256) {          // w1n [mf][och][slot]
      int mf = i >> 9, r = i & 511;
      int och = r >> 4, s = r & 15;
      int tp = mf * 4 + (s >> 2), ci = s & 3;
      w1n[i] = (ci < 3 && tp < 9) ? bf16rne(W1[och * 27 + ci * 9 + tp])
                                  : (unsigned short)0;
    }
    for (int i = tid; i < 4608; i += 256) {          // w2c [tap][oc][och] plain
      int tap = i >> 9, r = i & 511;
      int n = r >> 5, och = r & 31;
      int dy = tap / 3, dx = tap - dy * 3;
      w2c[i] = (n < 3) ? bf16rne(W2[((n * 32 + och) * 3 + dy) * 3 + dx])
                       : (unsigned short)0;
    }
    for (int i = tid; i < 1024; i += 256) {          // tcond
      int b = i >> 5, o = i & 31;
      tcond[i] = b1[o] + ((float)t[b] * (1.0f / NT_F)) * tw[o];
    }
    return;
  }

  __shared__ float vsp[32][288];   // padded cols: idx = col + 16
  __shared__ float gkl[32];
  int rg = blk & 7;
  int bc = blk >> 3;
  int b = bc / CH;
  int y0 = rg * 32;
  const float* xp = x + (size_t)bc * (HH * WW);

  // issue the 60 column loads first (independent of gk)
  float xv[60];
#pragma unroll
  for (int i = 0; i < 60; i++) {
    int gy = y0 - PAD + i;
    gy = (gy < 0) ? -gy : gy;
    gy = (gy >= HH) ? (2 * HH - 2 - gy) : gy;
    xv[i] = xp[gy * WW + tid];
  }

  // wave 0 computes this batch's gaussian kernel into LDS
  if (tid < 64) {
    float wexp = 0.0f;
    if (tid < KS) {
      float sigma = sched[t[b]];
      float xg = (float)(tid - PAD) / sigma;
      wexp = expf(-0.5f * xg * xg);
    }
    float s = wexp;
#pragma unroll
    for (int off = 32; off > 0; off >>= 1) s += __shfl_down(s, off);
    float tot = __shfl(s, 0);
    if (tid < 32) gkl[tid] = wexp / tot;
  }
  __syncthreads();

  float acc[32];
#pragma unroll
  for (int yy = 0; yy < 32; yy++) acc[yy] = 0.0f;
#pragma unroll
  for (int kk = 0; kk < KS; kk++) {
    float kv = gkl[kk];
#pragma unroll
    for (int yy = 0; yy < 32; yy++) acc[yy] += kv * xv[yy + kk];
  }
#pragma unroll
  for (int yy = 0; yy < 32; yy++) vsp[yy][tid + 16] = acc[yy];
  __syncthreads();
  {
    int row = tid >> 4, i2 = tid & 15;
#pragma unroll
    for (int r2 = 0; r2 < 2; r2++) {
      int rr = row + 16 * r2;
      vsp[rr][i2] = vsp[rr][32 - i2];
      vsp[rr][272 + i2] = vsp[rr][270 - i2];
    }
  }
  __syncthreads();

  size_t zb = (size_t)bc * (HH * WW);
#pragma unroll
  for (int it = 0; it < 8; ++it) {
    int unit = tid + 256 * it;
    int row = unit >> 6, cg = unit & 63;
    float w[36];
#pragma unroll
    for (int i = 0; i < 9; i++)
      *(float4*)&w[4 * i] = *(const float4*)&vsp[row][4 * (cg + i)];
    float o0 = 0, o1 = 0, o2 = 0, o3 = 0;
#pragma unroll
    for (int kk = 0; kk < KS; kk++) {
      float kv = gkl[kk];
      o0 += kv * w[2 + kk];
      o1 += kv * w[3 + kk];
      o2 += kv * w[4 + kk];
      o3 += kv * w[5 + kk];
    }
    unsigned u0 = pk_bf16(o0, o1);
    unsigned u1 = pk_bf16(o2, o3);
    *(uint2*)&z[zb + (size_t)(y0 + row) * WW + 4 * cg] = make_uint2(u0, u1);
  }
}

// ---------------- fused conv1+ReLU+conv2+MSE via bf16 MFMA ----------------
// grid (16,16,B); block 256 = 4 waves; 16x16 output tile
// conv1: 32x32x16 MFMA, 32-px groups, 3 accumulating MFMAs/group.
__global__ __launch_bounds__(256, 5) void convloss_kernel(
    const float* __restrict__ x, const float* __restrict__ ws,
    const float* __restrict__ b2g, float* __restrict__ partial) {
  __shared__ __align__(16) unsigned short zs4[400 * 4];   // [y*20+x][ci0..2,pad]
  __shared__ __align__(16) unsigned short hs[324 * 40];   // [p18][och(32)+pad8]
  __shared__ float wsum[4];

  const float* tcond = ws + 1024;
  const unsigned short* w1n = (const unsigned short*)(ws + 2048);
  const unsigned short* w2c = (const unsigned short*)(ws + 2816);
  const unsigned short* zg = (const unsigned short*)(ws + 5120);

  int bx = blockIdx.x, by = blockIdx.y, b = blockIdx.z;
  int tid = threadIdx.x;
  int x0 = bx * 16, y0 = by * 16;
  const unsigned short* zbp = zg + (size_t)b * 3 * HH * WW;

  int lane = tid & 63;
  int q = lane >> 4;        // quad (16x16 shapes)
  int col = lane & 15;      // 16x16 m/n index
  int col32 = lane & 31;    // 32x32 n index (pixel)
  int h = lane >> 5;        // 32x32 half
  int wv = tid >> 6;        // wave id

  // stage z tile (20x20), channel-interleaved, zero outside image
#pragma unroll
  for (int r = 0; r < 2; r++) {
    int unit = tid + 256 * r;
    if (unit < 400) {
      int zy = unit / 20, zx = unit - zy * 20;
      int gy = y0 - 2 + zy, gx = x0 - 2 + zx;
      unsigned c0 = 0, c1 = 0, c2 = 0;
      if ((unsigned)gy < (unsigned)HH && (unsigned)gx < (unsigned)WW) {
        int gi = gy * WW + gx;
        c0 = zbp[gi];
        c1 = zbp[HH * WW + gi];
        c2 = zbp[2 * HH * WW + gi];
      }
      *(uint2*)&zs4[unit * 4] = make_uint2(c0 | (c1 << 16), c2);
    }
  }

  // conv1 A fragments = weights [m=och][k=slot(h*8+j)]: b128 each
  U4 W0, W1f, W2f;
  W0.u4  = *(const uint4*)(w1n + 0 * 512 + col32 * 16 + h * 8);
  W1f.u4 = *(const uint4*)(w1n + 1 * 512 + col32 * 16 + h * 8);
  W2f.u4 = *(const uint4*)(w1n + 2 * 512 + col32 * 16 + h * 8);

  // conv1 C-init: tcond bias per (reg,h): och = (reg&3) + 8*(reg>>2) + 4h
  f32x16 tc16;
#pragma unroll
  for (int r1 = 0; r1 < 4; r1++) {
    float4 v = *(const float4*)(tcond + b * 32 + 4 * h + 8 * r1);
    tc16[4 * r1 + 0] = v.x;
    tc16[4 * r1 + 1] = v.y;
    tc16[4 * r1 + 2] = v.z;
    tc16[4 * r1 + 3] = v.w;
  }

  int colc = (col < 3) ? col : 0;
  float b2v = b2g[colc];

  __syncthreads();   // B1: z staged

  // per-lane b64 read offsets (ushort units) for the 3 MFMAs' tap pairs
  int oA0 = h ? 8 : 0, oB0 = h ? 80 : 4;
  int oA1 = h ? 160 : 84, oB1 = h ? 164 : 88;
  const int oA2 = 168;

  // ---- P1: conv1 -> h (18x18, 32 och); 32-px groups, 3 MFMAs each ----
#pragma unroll
  for (int i = 0; i < 3; i++) {
    int g = wv + 4 * i;
    if (g < 11) {                 // wave-uniform guard
      int p = g * 32 + col32;
      int pc = (p > 323) ? 323 : p;
      int py = pc / 18, px = pc - py * 18;
      int ub = (py * 20 + px) * 4;
      uint2 l0 = *(const uint2*)&zs4[ub + oA0];
      uint2 l1 = *(const uint2*)&zs4[ub + oB0];
      uint2 l2 = *(const uint2*)&zs4[ub + oA1];
      uint2 l3 = *(const uint2*)&zs4[ub + oB1];
      uint2 l4 = *(const uint2*)&zs4[ub + oA2];
      U4 Bz0, Bz1, Bz2;
      Bz0.u4 = make_uint4(l0.x, l0.y, l1.x, l1.y);
      Bz1.u4 = make_uint4(l2.x, l2.y, l3.x, l3.y);
      Bz2.u4 = make_uint4(l4.x, l4.y, 0u, 0u);
      f32x16 a = __builtin_amdgcn_mfma_f32_32x32x16_bf16(W0.s8, Bz0.s8, tc16, 0, 0, 0);
      a = __builtin_amdgcn_mfma_f32_32x32x16_bf16(W1f.s8, Bz1.s8, a, 0, 0, 0);
      a = __builtin_amdgcn_mfma_f32_32x32x16_bf16(W2f.s8, Bz2.s8, a, 0, 0, 0);
      if (p < 324) {
#pragma unroll
        for (int r1 = 0; r1 < 4; r1++) {
          unsigned u0 = pk_bf16(fmaxf(a[4 * r1 + 0], 0.0f), fmaxf(a[4 * r1 + 1], 0.0f));
          unsigned u1 = pk_bf16(fmaxf(a[4 * r1 + 2], 0.0f), fmaxf(a[4 * r1 + 3], 0.0f));
          *(uint2*)&hs[p * 40 + 4 * h + 8 * r1] = make_uint2(u0, u1);
        }
      }
    }
  }
  __syncthreads();   // B2: h complete

  // prefetch MSE x reads (hidden behind conv2)
  const float* xb = x + (size_t)b * 3 * HH * WW;
  float4 xpre[4];
#pragma unroll
  for (int i = 0; i < 4; i++) {
    int g2 = wv * 4 + i;
    xpre[i] = *(const float4*)&xb[colc * (HH * WW) + (y0 + g2) * WW + x0 + q * 4];
  }

  // ---- conv2, loop-rotated: 18 A-reads, 36 accumulating MFMAs ----
  const f32x4 bcv = {b2v, b2v, b2v, b2v};
  f32x4 dacc[4];
#pragma unroll
  for (int i = 0; i < 4; i++) dacc[i] = bcv;
  {
    const unsigned short* hbase = &hs[((wv * 4) * 18 + col) * 40 + q * 8];
#pragma unroll
    for (int dx = 0; dx < 3; dx++) {
      U4 Bt0, Bt1, Bt2;
      Bt0.u4 = *(const uint4*)(w2c + (0 * 3 + dx) * 512 + col * 32 + q * 8);
      Bt1.u4 = *(const uint4*)(w2c + (1 * 3 + dx) * 512 + col * 32 + q * 8);
      Bt2.u4 = *(const uint4*)(w2c + (2 * 3 + dx) * 512 + col * 32 + q * 8);
#pragma unroll
      for (int rr = 0; rr < 6; rr++) {
        U4 A;
        A.u4 = *(const uint4*)&hbase[(rr * 18 + dx) * 40];   // one b128, imm offset
        if (rr < 4)
          dacc[rr] = __builtin_amdgcn_mfma_f32_16x16x32_bf16(A.s8, Bt0.s8, dacc[rr], 0, 0, 0);
        if (rr >= 1 && rr < 5)
          dacc[rr - 1] = __builtin_amdgcn_mfma_f32_16x16x32_bf16(A.s8, Bt1.s8, dacc[rr - 1], 0, 0, 0);
        if (rr >= 2)
          dacc[rr - 2] = __builtin_amdgcn_mfma_f32_16x16x32_bf16(A.s8, Bt2.s8, dacc[rr - 2], 0, 0, 0);
      }
    }
  }

  // ---- MSE partial (oc=col<3, ox=q*4+r, oy=wv*4+i) ----
  float s = 0.0f;
  if (col < 3) {
#pragma unroll
    for (int i = 0; i < 4; i++) {
      float4 xv = xpre[i];
      float d0 = xv.x - dacc[i][0];
      float d1 = xv.y - dacc[i][1];
      float d2 = xv.z - dacc[i][2];
      float d3 = xv.w - dacc[i][3];
      s += d0 * d0 + d1 * d1 + d2 * d2 + d3 * d3;
    }
  }
#pragma unroll
  for (int off = 32; off > 0; off >>= 1) s += __shfl_down(s, off);
  if (lane == 0) wsum[wv] = s;
  __syncthreads();   // B3
  if (tid == 0) {
    int bid = (b * 16 + by) * 16 + bx;
    partial[bid] = wsum[0] + wsum[1] + wsum[2] + wsum[3];
  }
}

// ---------------- final reduce: 8192 partials -> out[0] ----------------
__global__ __launch_bounds__(256) void reduce_kernel(const float* __restrict__ partial,
                                                     float* __restrict__ out) {
  __shared__ float wsum[4];
  int tid = threadIdx.x;
  float s = 0.0f;
#pragma unroll
  for (int i = 0; i < 8; i++) {
    float4 v = *(const float4*)&partial[(tid + 256 * i) * 4];
    s += v.x + v.y + v.z + v.w;
  }
#pragma unroll
  for (int off = 32; off > 0; off >>= 1) s += __shfl_down(s, off);
  if ((tid & 63) == 0) wsum[tid >> 6] = s;
  __syncthreads();
  if (tid == 0)
    out[0] = (wsum[0] + wsum[1] + wsum[2] + wsum[3]) * (1.0f / 6291456.0f);
}

extern "C" void kernel_launch(void* const* d_in, const int* in_sizes, int n_in,
                              void* d_out, int out_size, void* d_ws, size_t ws_size,
                              hipStream_t stream) {
  const float* x = (const float*)d_in[0];
  const int* t = (const int*)d_in[1];
  const float* W1 = (const float*)d_in[2];
  const float* b1 = (const float*)d_in[3];
  const float* tw = (const float*)d_in[4];
  const float* W2 = (const float*)d_in[5];
  const float* b2 = (const float*)d_in[6];
  const float* sched = (const float*)d_in[7];
  float* out = (float*)d_out;
  float* ws = (float*)d_ws;
  unsigned short* z = (unsigned short*)(ws + 5120);
  float* partial = ws + PARTIAL_OFF;

  blur_kernel<<<BATCH * CH * 8 + 1, 256, 0, stream>>>(x, t, sched, W1, b1, tw, W2, ws, z);
  dim3 grid(16, 16, BATCH);
  convloss_kernel<<<grid, 256, 0, stream>>>(x, ws, b2, partial);
  reduce_kernel<<<1, 256, 0, stream>>>(partial, out);
}

// Round 13
// 139.735 us; speedup vs baseline: 1.6769x; 1.0059x over previous
//
#include <hip/hip_runtime.h>
#include <hip/hip_bf16.h>

#define BATCH 32
#define CH 3
#define HH 256
#define WW 256
#define KS 29
#define PAD 14
#define NT_F 1000.0f

typedef __attribute__((ext_vector_type(8))) short short8;
typedef __attribute__((ext_vector_type(4))) float f32x4;
typedef __attribute__((ext_vector_type(16))) float f32x16;

union U4 { short8 s8; uint4 u4; };

__device__ inline unsigned short bf16rne(float f) {
  unsigned u = __float_as_uint(f);
  unsigned r = (u + 0x7FFFu + ((u >> 16) & 1u)) >> 16;
  return (unsigned short)r;
}
__device__ inline unsigned pk_bf16(float a, float b) {
  union { __hip_bfloat162 h2; unsigned u; } cv;
  cv.h2 = __float22bfloat162_rn(make_float2(a, b));
  return cv.u;
}

// ws float layout:
//   (unused)  [1024]          @ 0
//   tcond [32][32]            @ 1024
//   w1n   ushort[3][32][16]   @ 2048  ([mf][och][slot]; slot s: tap=mf*4+(s>>2), ci=s&3)
//   w2c   ushort[9][16][32]   @ 2816  ([tap][oc(16)][och] plain order)
//   z     ushort[32][3][256][256] @ 5120  (bf16 blurred)
//   partial float[8192]       @ 3151872
//
// conv1 (32x32x16 MFMA): A=weights[m=och][k=slot], B=z[k=slot][n=pixel],
//   D[n=pixel=lane&31][m=och=(reg&3)+8*(reg>>2)+4*(lane>>5)]
// conv2 (16x16x32 MFMA): hs & w2c in plain och order.

#define PARTIAL_OFF 3151872

// ---------------- blur (+ embedded weight-prep in block 768) ----------------
__global__ __launch_bounds__(256, 3) void blur_kernel(
    const float* __restrict__ x, const int* __restrict__ t,
    const float* __restrict__ sched, const float* __restrict__ W1,
    const float* __restrict__ b1, const float* __restrict__ tw,
    const float* __restrict__ W2, float* __restrict__ ws,
    unsigned short* __restrict__ z) {
  int blk = blockIdx.x;
  int tid = threadIdx.x;

  if (blk >= BATCH * CH * 8) {
    // ---- weight-prep block (runs once; convloss launches after this kernel)
    float* tcond = ws + 1024;
    unsigned short* w1n = (unsigned short*)(ws + 2048);
    unsigned short* w2c = (unsigned short*)(ws + 2816);
    for (int i = tid; i < 1536; i += 256) {          // w1n [mf][och][slot]
      int mf = i >> 9, r = i & 511;
      int och = r >> 4, s = r & 15;
      int tp = mf * 4 + (s >> 2), ci = s & 3;
      w1n[i] = (ci < 3 && tp < 9) ? bf16rne(W1[och * 27 + ci * 9 + tp])
                                  : (unsigned short)0;
    }
    for (int i = tid; i < 4608; i += 256) {          // w2c [tap][oc][och] plain
      int tap = i >> 9, r = i & 511;
      int n = r >> 5, och = r & 31;
      int dy = tap / 3, dx = tap - dy * 3;
      w2c[i] = (n < 3) ? bf16rne(W2[((n * 32 + och) * 3 + dy) * 3 + dx])
                       : (unsigned short)0;
    }
    for (int i = tid; i < 1024; i += 256) {          // tcond
      int b = i >> 5, o = i & 31;
      tcond[i] = b1[o] + ((float)t[b] * (1.0f / NT_F)) * tw[o];
    }
    return;
  }

  __shared__ float vsp[32][288];   // padded cols: idx = col + 16
  __shared__ float gkl[32];
  int rg = blk & 7;
  int bc = blk >> 3;
  int b = bc / CH;
  int y0 = rg * 32;
  const float* xp = x + (size_t)bc * (HH * WW);

  // issue the 60 column loads first (independent of gk)
  float xv[60];
#pragma unroll
  for (int i = 0; i < 60; i++) {
    int gy = y0 - PAD + i;
    gy = (gy < 0) ? -gy : gy;
    gy = (gy >= HH) ? (2 * HH - 2 - gy) : gy;
    xv[i] = xp[gy * WW + tid];
  }

  // wave 0 computes this batch's gaussian kernel into LDS
  if (tid < 64) {
    float wexp = 0.0f;
    if (tid < KS) {
      float sigma = sched[t[b]];
      float xg = (float)(tid - PAD) / sigma;
      wexp = expf(-0.5f * xg * xg);
    }
    float s = wexp;
#pragma unroll
    for (int off = 32; off > 0; off >>= 1) s += __shfl_down(s, off);
    float tot = __shfl(s, 0);
    if (tid < 32) gkl[tid] = wexp / tot;
  }
  __syncthreads();

  float acc[32];
#pragma unroll
  for (int yy = 0; yy < 32; yy++) acc[yy] = 0.0f;
#pragma unroll
  for (int kk = 0; kk < KS; kk++) {
    float kv = gkl[kk];
#pragma unroll
    for (int yy = 0; yy < 32; yy++) acc[yy] += kv * xv[yy + kk];
  }
#pragma unroll
  for (int yy = 0; yy < 32; yy++) vsp[yy][tid + 16] = acc[yy];
  __syncthreads();
  {
    int row = tid >> 4, i2 = tid & 15;
#pragma unroll
    for (int r2 = 0; r2 < 2; r2++) {
      int rr = row + 16 * r2;
      vsp[rr][i2] = vsp[rr][32 - i2];
      vsp[rr][272 + i2] = vsp[rr][270 - i2];
    }
  }
  __syncthreads();

  size_t zb = (size_t)bc * (HH * WW);
#pragma unroll
  for (int it = 0; it < 8; ++it) {
    int unit = tid + 256 * it;
    int row = unit >> 6, cg = unit & 63;
    float w[36];
#pragma unroll
    for (int i = 0; i < 9; i++)
      *(float4*)&w[4 * i] = *(const float4*)&vsp[row][4 * (cg + i)];
    float o0 = 0, o1 = 0, o2 = 0, o3 = 0;
#pragma unroll
    for (int kk = 0; kk < KS; kk++) {
      float kv = gkl[kk];
      o0 += kv * w[2 + kk];
      o1 += kv * w[3 + kk];
      o2 += kv * w[4 + kk];
      o3 += kv * w[5 + kk];
    }
    unsigned u0 = pk_bf16(o0, o1);
    unsigned u1 = pk_bf16(o2, o3);
    *(uint2*)&z[zb + (size_t)(y0 + row) * WW + 4 * cg] = make_uint2(u0, u1);
  }
}

// ---------------- fused conv1+ReLU+conv2+MSE via bf16 MFMA ----------------
// grid (16,16,B); block 256 = 4 waves; 16x16 output tile
// conv1: 32x32x16 MFMA, 32-px groups; conv2: 16x16x32, loop-rotated.
__global__ __launch_bounds__(256, 5) void convloss_kernel(
    const float* __restrict__ x, const float* __restrict__ ws,
    const float* __restrict__ b2g, float* __restrict__ partial) {
  __shared__ __align__(16) unsigned short zs4[400 * 4];   // [y*20+x][ci0..2,pad]
  __shared__ __align__(16) unsigned short hs[324 * 40];   // [p18][och(32)+pad8]
  __shared__ float wsum[4];

  const float* tcond = ws + 1024;
  const unsigned short* w1n = (const unsigned short*)(ws + 2048);
  const unsigned short* w2c = (const unsigned short*)(ws + 2816);
  const unsigned short* zg = (const unsigned short*)(ws + 5120);

  int bx = blockIdx.x, by = blockIdx.y, b = blockIdx.z;
  int tid = threadIdx.x;
  int x0 = bx * 16, y0 = by * 16;
  const unsigned short* zbp = zg + (size_t)b * 3 * HH * WW;

  int lane = tid & 63;
  int q = lane >> 4;        // quad (16x16 shapes)
  int col = lane & 15;      // 16x16 m/n index
  int col32 = lane & 31;    // 32x32 n index (pixel)
  int h = lane >> 5;        // 32x32 half
  int wv = tid >> 6;        // wave id

  // ---- vectorized z staging: 200 threads, 2-px units, b32 loads ----
  // tile px pair p0 = zy*20 + 2*zx2 (zy = unit/10, zx2 = unit%10); pairs are
  // always fully in- or fully out-of-image (gx0 even), so mask per pair.
  if (tid < 200) {
    int zy = tid / 10;
    int zx2 = tid - zy * 10;
    int gy = y0 - 2 + zy;
    int gx0 = x0 - 2 + 2 * zx2;
    bool ok = ((unsigned)gy < (unsigned)HH) && ((unsigned)gx0 < (unsigned)(WW - 1));
    int cy = (gy < 0) ? 0 : ((gy > 255) ? 255 : gy);
    int cx = (gx0 < 0) ? 0 : ((gx0 > 254) ? 254 : gx0);
    int gi = cy * WW + cx;
    unsigned c0 = *(const unsigned*)&zbp[gi];
    unsigned c1 = *(const unsigned*)&zbp[HH * WW + gi];
    unsigned c2 = *(const unsigned*)&zbp[2 * HH * WW + gi];
    unsigned m = ok ? 0xFFFFFFFFu : 0u;
    c0 &= m; c1 &= m; c2 &= m;
    uint4 o;
    o.x = (c0 & 0xFFFFu) | (c1 << 16);        // px0: ci0,ci1
    o.y = c2 & 0xFFFFu;                       // px0: ci2,pad
    o.z = (c0 >> 16) | (c1 & 0xFFFF0000u);    // px1: ci0,ci1
    o.w = c2 >> 16;                           // px1: ci2,pad
    *(uint4*)&zs4[(zy * 20 + 2 * zx2) * 4] = o;
  }

  // conv1 A fragments = weights [m=och][k=slot(h*8+j)]: b128 each
  U4 W0, W1f, W2f;
  W0.u4  = *(const uint4*)(w1n + 0 * 512 + col32 * 16 + h * 8);
  W1f.u4 = *(const uint4*)(w1n + 1 * 512 + col32 * 16 + h * 8);
  W2f.u4 = *(const uint4*)(w1n + 2 * 512 + col32 * 16 + h * 8);

  // conv1 C-init: tcond bias per (reg,h): och = (reg&3) + 8*(reg>>2) + 4h
  f32x16 tc16;
#pragma unroll
  for (int r1 = 0; r1 < 4; r1++) {
    float4 v = *(const float4*)(tcond + b * 32 + 4 * h + 8 * r1);
    tc16[4 * r1 + 0] = v.x;
    tc16[4 * r1 + 1] = v.y;
    tc16[4 * r1 + 2] = v.z;
    tc16[4 * r1 + 3] = v.w;
  }

  int colc = (col < 3) ? col : 0;
  float b2v = b2g[colc];

  __syncthreads();   // B1: z staged

  // per-lane b64 read offsets (ushort units) for the 3 MFMAs' tap pairs
  int oA0 = h ? 8 : 0, oB0 = h ? 80 : 4;
  int oA1 = h ? 160 : 84, oB1 = h ? 164 : 88;
  const int oA2 = 168;

  // ---- P1: conv1 -> h (18x18, 32 och); 32-px groups, 3 MFMAs each ----
#pragma unroll
  for (int i = 0; i < 3; i++) {
    int g = wv + 4 * i;
    if (g < 11) {                 // wave-uniform guard
      int p = g * 32 + col32;
      int pc = (p > 323) ? 323 : p;
      int py = pc / 18, px = pc - py * 18;
      int ub = (py * 20 + px) * 4;
      uint2 l0 = *(const uint2*)&zs4[ub + oA0];
      uint2 l1 = *(const uint2*)&zs4[ub + oB0];
      uint2 l2 = *(const uint2*)&zs4[ub + oA1];
      uint2 l3 = *(const uint2*)&zs4[ub + oB1];
      uint2 l4 = *(const uint2*)&zs4[ub + oA2];
      U4 Bz0, Bz1, Bz2;
      Bz0.u4 = make_uint4(l0.x, l0.y, l1.x, l1.y);
      Bz1.u4 = make_uint4(l2.x, l2.y, l3.x, l3.y);
      Bz2.u4 = make_uint4(l4.x, l4.y, 0u, 0u);
      f32x16 a = __builtin_amdgcn_mfma_f32_32x32x16_bf16(W0.s8, Bz0.s8, tc16, 0, 0, 0);
      a = __builtin_amdgcn_mfma_f32_32x32x16_bf16(W1f.s8, Bz1.s8, a, 0, 0, 0);
      a = __builtin_amdgcn_mfma_f32_32x32x16_bf16(W2f.s8, Bz2.s8, a, 0, 0, 0);
      if (p < 324) {
#pragma unroll
        for (int r1 = 0; r1 < 4; r1++) {
          unsigned u0 = pk_bf16(fmaxf(a[4 * r1 + 0], 0.0f), fmaxf(a[4 * r1 + 1], 0.0f));
          unsigned u1 = pk_bf16(fmaxf(a[4 * r1 + 2], 0.0f), fmaxf(a[4 * r1 + 3], 0.0f));
          *(uint2*)&hs[p * 40 + 4 * h + 8 * r1] = make_uint2(u0, u1);
        }
      }
    }
  }
  __syncthreads();   // B2: h complete

  // prefetch MSE x reads (hidden behind conv2)
  const float* xb = x + (size_t)b * 3 * HH * WW;
  float4 xpre[4];
#pragma unroll
  for (int i = 0; i < 4; i++) {
    int g2 = wv * 4 + i;
    xpre[i] = *(const float4*)&xb[colc * (HH * WW) + (y0 + g2) * WW + x0 + q * 4];
  }

  // hoist all 9 conv2 B-frags: one addr calc, back-to-back loads
  U4 Bt[3][3];
  {
    const unsigned short* wbase = w2c + col * 32 + q * 8;
#pragma unroll
    for (int dy = 0; dy < 3; dy++)
#pragma unroll
      for (int dx = 0; dx < 3; dx++)
        Bt[dy][dx].u4 = *(const uint4*)(wbase + (dy * 3 + dx) * 512);
  }

  // ---- conv2, loop-rotated: 18 A-reads, 36 accumulating MFMAs ----
  const f32x4 bcv = {b2v, b2v, b2v, b2v};
  f32x4 dacc[4];
#pragma unroll
  for (int i = 0; i < 4; i++) dacc[i] = bcv;
  {
    const unsigned short* hbase = &hs[((wv * 4) * 18 + col) * 40 + q * 8];
#pragma unroll
    for (int dx = 0; dx < 3; dx++) {
#pragma unroll
      for (int rr = 0; rr < 6; rr++) {
        U4 A;
        A.u4 = *(const uint4*)&hbase[(rr * 18 + dx) * 40];   // one b128, imm offset
        if (rr < 4)
          dacc[rr] = __builtin_amdgcn_mfma_f32_16x16x32_bf16(A.s8, Bt[0][dx].s8, dacc[rr], 0, 0, 0);
        if (rr >= 1 && rr < 5)
          dacc[rr - 1] = __builtin_amdgcn_mfma_f32_16x16x32_bf16(A.s8, Bt[1][dx].s8, dacc[rr - 1], 0, 0, 0);
        if (rr >= 2)
          dacc[rr - 2] = __builtin_amdgcn_mfma_f32_16x16x32_bf16(A.s8, Bt[2][dx].s8, dacc[rr - 2], 0, 0, 0);
      }
    }
  }

  // ---- MSE partial (oc=col<3, ox=q*4+r, oy=wv*4+i) ----
  float s = 0.0f;
  if (col < 3) {
#pragma unroll
    for (int i = 0; i < 4; i++) {
      float4 xv = xpre[i];
      float d0 = xv.x - dacc[i][0];
      float d1 = xv.y - dacc[i][1];
      float d2 = xv.z - dacc[i][2];
      float d3 = xv.w - dacc[i][3];
      s += d0 * d0 + d1 * d1 + d2 * d2 + d3 * d3;
    }
  }
#pragma unroll
  for (int off = 32; off > 0; off >>= 1) s += __shfl_down(s, off);
  if (lane == 0) wsum[wv] = s;
  __syncthreads();   // B3
  if (tid == 0) {
    int bid = (b * 16 + by) * 16 + bx;
    partial[bid] = wsum[0] + wsum[1] + wsum[2] + wsum[3];
  }
}

// ---------------- final reduce: 8192 partials -> out[0] ----------------
__global__ __launch_bounds__(256) void reduce_kernel(const float* __restrict__ partial,
                                                     float* __restrict__ out) {
  __shared__ float wsum[4];
  int tid = threadIdx.x;
  float s = 0.0f;
#pragma unroll
  for (int i = 0; i < 8; i++) {
    float4 v = *(const float4*)&partial[(tid + 256 * i) * 4];
    s += v.x + v.y + v.z + v.w;
  }
#pragma unroll
  for (int off = 32; off > 0; off >>= 1) s += __shfl_down(s, off);
  if ((tid & 63) == 0) wsum[tid >> 6] = s;
  __syncthreads();
  if (tid == 0)
    out[0] = (wsum[0] + wsum[1] + wsum[2] + wsum[3]) * (1.0f / 6291456.0f);
}

extern "C" void kernel_launch(void* const* d_in, const int* in_sizes, int n_in,
                              void* d_out, int out_size, void* d_ws, size_t ws_size,
                              hipStream_t stream) {
  const float* x = (const float*)d_in[0];
  const int* t = (const int*)d_in[1];
  const float* W1 = (const float*)d_in[2];
  const float* b1 = (const float*)d_in[3];
  const float* tw = (const float*)d_in[4];
  const float* W2 = (const float*)d_in[5];
  const float* b2 = (const float*)d_in[6];
  const float* sched = (const float*)d_in[7];
  float* out = (float*)d_out;
  float* ws = (float*)d_ws;
  unsigned short* z = (unsigned short*)(ws + 5120);
  float* partial = ws + PARTIAL_OFF;

  blur_kernel<<<BATCH * CH * 8 + 1, 256, 0, stream>>>(x, t, sched, W1, b1, tw, W2, ws, z);
  dim3 grid(16, 16, BATCH);
  convloss_kernel<<<grid, 256, 0, stream>>>(x, ws, b2, partial);
  reduce_kernel<<<1, 256, 0, stream>>>(partial, out);
}